// Round 1
// 1661.458 us; speedup vs baseline: 1.0426x; 1.0426x over previous
//
#include <hip/hip_runtime.h>
#include <hip/hip_bf16.h>

typedef __attribute__((ext_vector_type(4))) float f32x4;
typedef __attribute__((ext_vector_type(8))) short short8;
typedef __attribute__((ext_vector_type(8))) unsigned short ushort8;
typedef __attribute__((ext_vector_type(4))) unsigned short ushort4v;
typedef __attribute__((ext_vector_type(4))) unsigned int uint4v;

#define DEVFN __device__ __forceinline__

DEVFN float b2f(unsigned short u) { return __uint_as_float(((unsigned)u) << 16); }
DEVFN unsigned short f2b(float f) {
  __hip_bfloat16 h = __float2bfloat16(f);
  return __builtin_bit_cast(unsigned short, h);
}

DEVFN void load_lds16(const void* g, void* l) {
  __builtin_amdgcn_global_load_lds(
      (const __attribute__((address_space(1))) unsigned int*)g,
      (__attribute__((address_space(3))) unsigned int*)l, 16, 0, 0);
}

// ===========================================================================

__global__ void fill_out_zero(float* o, int n) {
  int i = blockIdx.x * 256 + threadIdx.x;
  if (i < n) o[i] = 0.0f;
}

__global__ __launch_bounds__(256) void init_x(
    const float* __restrict__ xin, const float* __restrict__ bvec,
    float* __restrict__ x, unsigned short* __restrict__ xb) {
  size_t i = (size_t)blockIdx.x * 256 + threadIdx.x;
  int col = (int)(i % 768);
  float v = xin[i] - bvec[col];
  x[i] = v;
  xb[i] = f2b(v);
}

// buf[i] = bias[i % ld] (or 0 if bias null)
__global__ __launch_bounds__(256) void fill_bias(
    float* __restrict__ buf, const float* __restrict__ bias, int ld) {
  size_t i = (size_t)blockIdx.x * 256 + threadIdx.x;
  buf[i] = bias ? bias[(int)(i % ld)] : 0.0f;
}

// f32 -> bf16 straight convert, 4 elems/thread (n must be /1024)
__global__ __launch_bounds__(256) void conv_f2b(
    const float* __restrict__ in, unsigned short* __restrict__ out) {
  size_t i = ((size_t)blockIdx.x * 256 + threadIdx.x) * 4;
  f32x4 v = *(const f32x4*)(in + i);
  ushort4v w;
#pragma unroll
  for (int e = 0; e < 4; ++e) w[e] = f2b(v[e]);
  *(ushort4v*)(out + i) = w;
}

// out[c][r] = bf16(in[r][c]); R,C multiples of 32; grid (R/32, C/32)
__global__ __launch_bounds__(256) void transpose_f2b(
    const float* __restrict__ in, unsigned short* __restrict__ out,
    int R, int C) {
  __shared__ float tile[32][33];
  int r0 = blockIdx.x * 32, c0 = blockIdx.y * 32;
  int tx = threadIdx.x & 31, ty = threadIdx.x >> 5;
#pragma unroll
  for (int i = 0; i < 4; ++i)
    tile[ty + i * 8][tx] = in[(size_t)(r0 + ty + i * 8) * C + c0 + tx];
  __syncthreads();
#pragma unroll
  for (int i = 0; i < 4; ++i)
    out[(size_t)(c0 + ty + i * 8) * R + r0 + tx] = f2b(tile[tx][ty + i * 8]);
}

// ---------------------------------------------------------------------------
// gemm_bt2: C[M,N] = epi(alpha * A[M,K] . B[N,K]^T + bias)  both bf16 K-major.
// 128x128 tile, BK=64, global_load_lds staging (conflict-free).
// SC=1: C rows shifted per batch (z storage [b][1+1024][W]).
// ---------------------------------------------------------------------------
template <typename CT, bool RELU, int SC, bool BIAS, bool SPLITK>
__global__ __launch_bounds__(256) void gemm_bt2(
    const unsigned short* __restrict__ A, const unsigned short* __restrict__ B,
    CT* __restrict__ C, const float* __restrict__ bias,
    int K, int ldc, float alpha) {
  __shared__ unsigned short sA[128 * 64];
  __shared__ unsigned short sB[128 * 64];
  const int tid = threadIdx.x;
  const int wave = tid >> 6, lane = tid & 63;
  const int row0 = blockIdx.x * 128, col0 = blockIdx.y * 128;
  const unsigned short* Ab = A + (size_t)row0 * K;
  const unsigned short* Bb = B + (size_t)col0 * K;
  const int srow = lane >> 3;
  const int scol = (lane & 7) * 8;
  const int wm = wave & 1, wn = wave >> 1;
  const int lr = lane & 15;
  const int lk = (lane >> 4) * 8;
  const int klen = SPLITK ? (K / (int)gridDim.z) : K;
  const int kbeg = SPLITK ? (int)blockIdx.z * klen : 0;
  f32x4 acc[4][4] = {};
  for (int k0 = kbeg; k0 < kbeg + klen; k0 += 64) {
#pragma unroll
    for (int it = 0; it < 4; ++it) {
      int chunk = wave * 4 + it;
      int r = chunk * 8 + srow;
      load_lds16(Ab + (size_t)r * K + k0 + scol, &sA[chunk * 512]);
      load_lds16(Bb + (size_t)r * K + k0 + scol, &sB[chunk * 512]);
    }
    __syncthreads();
#pragma unroll
    for (int ks = 0; ks < 2; ++ks) {
      short8 af[4], bfr[4];
#pragma unroll
      for (int i = 0; i < 4; ++i)
        af[i] = *(const short8*)&sA[(wm * 64 + i * 16 + lr) * 64 + ks * 32 + lk];
#pragma unroll
      for (int i = 0; i < 4; ++i)
        bfr[i] = *(const short8*)&sB[(wn * 64 + i * 16 + lr) * 64 + ks * 32 + lk];
#pragma unroll
      for (int i = 0; i < 4; ++i)
#pragma unroll
        for (int j = 0; j < 4; ++j)
          acc[i][j] = __builtin_amdgcn_mfma_f32_16x16x32_bf16(af[i], bfr[j], acc[i][j], 0, 0, 0);
    }
    __syncthreads();
  }
  const int rc = (SC == 0) ? 0 : ((row0 >> 10) + 1);
  const int rbase = row0 + rc + wm * 64 + (lane >> 4) * 4;
  const int cbase = col0 + wn * 64 + lr;
#pragma unroll
  for (int j = 0; j < 4; ++j) {
    int col = cbase + j * 16;
    float bv = BIAS ? bias[col] : 0.0f;
#pragma unroll
    for (int i = 0; i < 4; ++i) {
#pragma unroll
      for (int r = 0; r < 4; ++r) {
        float vv = acc[i][j][r] * alpha;
        size_t off = (size_t)(rbase + i * 16 + r) * ldc + col;
        if constexpr (SPLITK) {
          atomicAdd((float*)C + off, vv);
        } else {
          vv += bv;
          if (RELU) vv = fmaxf(vv, 0.0f);
          if constexpr (sizeof(CT) == 2) ((unsigned short*)C)[off] = f2b(vv);
          else C[off] = vv;
        }
      }
    }
  }
}

// ---------------------------------------------------------------------------
// gemm_qkv: fused q/k/v projection. blockIdx.z = weight index (0=q,1=k,2=v).
// C[4096,192] (f32, atomic) += A_zin . B_z[192,12288]^T
// BM=128, BN=192, BK=64, waves 2x2 (64x96 each); grid (32 rows, 8 k-splits, 3).
// A is always the z_in view. k/v (z>0): store row t -> t+1 within batch,
// dropping in-batch row 1023 (z_ctx shift done at write time).
// ---------------------------------------------------------------------------
__global__ __launch_bounds__(256) void gemm_qkv(
    const unsigned short* __restrict__ A, const unsigned short* __restrict__ Bq,
    float* __restrict__ qb, float* __restrict__ kb, float* __restrict__ vb) {
  __shared__ unsigned short sA[128 * 64];   // 16 KB
  __shared__ unsigned short sB[192 * 64];   // 24 KB
  const int tid = threadIdx.x;
  const int wave = tid >> 6, lane = tid & 63;
  const int wz = (int)blockIdx.z;           // 0=q, 1=k, 2=v
  const int shift = (wz > 0);
  const unsigned short* B = Bq + (size_t)wz * 192 * 12288;
  float* C = (wz == 0) ? qb : (wz == 1 ? kb : vb);
  const int row0 = blockIdx.x * 128;
  const int ra = (row0 >> 10) + 1;          // z_in view
  const unsigned short* Ab = A + (size_t)(row0 + ra) * 12288;
  const int srow = lane >> 3;
  const int scol = (lane & 7) * 8;
  const int wm = wave & 1, wn = wave >> 1;
  const int lr = lane & 15;
  const int lk = (lane >> 4) * 8;
  const int kbeg = (int)blockIdx.y * 1536;  // 12288/8
  f32x4 acc[4][6] = {};
  for (int k0 = kbeg; k0 < kbeg + 1536; k0 += 64) {
    // 40 chunks of 8 rows: 0..15 = A, 16..39 = B; 10 per wave
#pragma unroll
    for (int it = 0; it < 10; ++it) {
      int c = wave * 10 + it;
      if (c < 16) {
        int r = c * 8 + srow;
        load_lds16(Ab + (size_t)r * 12288 + k0 + scol, &sA[c * 512]);
      } else {
        int cb = c - 16;
        int r = cb * 8 + srow;
        load_lds16(B + (size_t)r * 12288 + k0 + scol, &sB[cb * 512]);
      }
    }
    __syncthreads();
#pragma unroll
    for (int ks = 0; ks < 2; ++ks) {
      short8 af[4], bfr[6];
#pragma unroll
      for (int i = 0; i < 4; ++i)
        af[i] = *(const short8*)&sA[(wm * 64 + i * 16 + lr) * 64 + ks * 32 + lk];
#pragma unroll
      for (int j = 0; j < 6; ++j)
        bfr[j] = *(const short8*)&sB[(wn * 96 + j * 16 + lr) * 64 + ks * 32 + lk];
#pragma unroll
      for (int i = 0; i < 4; ++i)
#pragma unroll
        for (int j = 0; j < 6; ++j)
          acc[i][j] = __builtin_amdgcn_mfma_f32_16x16x32_bf16(af[i], bfr[j], acc[i][j], 0, 0, 0);
    }
    __syncthreads();
  }
  const int rbase = row0 + wm * 64 + (lane >> 4) * 4;
  const int cbase = wn * 96 + lr;
#pragma unroll
  for (int j = 0; j < 6; ++j) {
    int col = cbase + j * 16;
#pragma unroll
    for (int i = 0; i < 4; ++i)
#pragma unroll
      for (int r = 0; r < 4; ++r) {
        int rw = rbase + i * 16 + r;
        if (shift) {
          if ((rw & 1023) == 1023) continue;  // dropped (next batch's row 0 = bias)
          rw += 1;
        }
        atomicAdd(C + (size_t)rw * 192 + col, acc[i][j][r]);
      }
  }
}

// ---------------------------------------------------------------------------
// Attention, two-pass flash-decode.
// Pass 1: task = (b,h,qgroup16,kchunk128). 9216 uniform wave-tasks, 4/block.
//   Per (b,h): 288 tasks; group g8=qg>>3 has 8 qgroups x (g8+1) chunks,
//   cumulative offset 4*g8*(g8+1). Partials P[task][qi] = {m, l, ov[24]}
//   (stride 28 floats) land in scratch (dead zbuf region).
// Pass 2: merge <=8 chunks per query; thread = (query; h,d).
// ---------------------------------------------------------------------------
__global__ __launch_bounds__(256) void attn_pass1(
    const float* __restrict__ q, const float* __restrict__ k,
    const float* __restrict__ v, float* __restrict__ P) {
  const int wave = threadIdx.x >> 6, lane = threadIdx.x & 63;
  const int task = (int)blockIdx.x * 4 + wave;  // 0..9215
  const int bh = task / 288, t = task % 288;
  const int b = bh >> 3, h = bh & 7;
  int g8 = 0;
  while (4 * (g8 + 1) * (g8 + 2) <= t) ++g8;
  const int r = t - 4 * g8 * (g8 + 1);
  const int qg = g8 * 8 + r / (g8 + 1);
  const int chunk = r % (g8 + 1);
  const int qi = lane & 15, ks = lane >> 4;
  const int qpos = qg * 16 + qi;
  const int n = b * 1024 + qpos;
  const float scale = 0.20412414523193154f;  // 1/sqrt(24)
  float qv[24];
  const float* qr = q + (size_t)n * 192 + h * 24;
#pragma unroll
  for (int d = 0; d < 24; ++d) qv[d] = qr[d] * scale;
  float m = -1e30f, l = 0.0f, ov[24] = {};
  const float* kbp = k + (size_t)b * 1024 * 192 + h * 24;
  const float* vbp = v + (size_t)b * 1024 * 192 + h * 24;
  const int kend = min(qpos, chunk * 128 + 127);
  for (int kp = chunk * 128 + ks; kp <= kend; kp += 4) {
    const f32x4* kr = (const f32x4*)(kbp + (size_t)kp * 192);
    float s0 = 0.0f, s1 = 0.0f, s2 = 0.0f;
#pragma unroll
    for (int j = 0; j < 2; ++j) {
      f32x4 k0 = kr[j * 3 + 0], k1 = kr[j * 3 + 1], k2 = kr[j * 3 + 2];
#pragma unroll
      for (int e = 0; e < 4; ++e) {
        s0 += qv[(j * 3 + 0) * 4 + e] * k0[e];
        s1 += qv[(j * 3 + 1) * 4 + e] * k1[e];
        s2 += qv[(j * 3 + 2) * 4 + e] * k2[e];
      }
    }
    float s = s0 + s1 + s2;
    float mn = fmaxf(m, s);
    float corr = __expf(m - mn);
    float p = __expf(s - mn);
    const f32x4* vr = (const f32x4*)(vbp + (size_t)kp * 192);
    l = l * corr + p;
#pragma unroll
    for (int j = 0; j < 6; ++j) {
      f32x4 vvv = vr[j];
#pragma unroll
      for (int e = 0; e < 4; ++e) ov[j * 4 + e] = ov[j * 4 + e] * corr + p * vvv[e];
    }
    m = mn;
  }
  // merge the 4 k-slices (lanes qi, qi+16, qi+32, qi+48)
#pragma unroll
  for (int off = 16; off < 64; off <<= 1) {
    float m2 = __shfl_xor(m, off);
    float l2 = __shfl_xor(l, off);
    float mn = fmaxf(m, m2);
    float c1 = __expf(m - mn), c2 = __expf(m2 - mn);
    l = l * c1 + l2 * c2;
#pragma unroll
    for (int d = 0; d < 24; ++d) {
      float o2 = __shfl_xor(ov[d], off);
      ov[d] = ov[d] * c1 + o2 * c2;
    }
    m = mn;
  }
  if (ks == 0) {
    float* pr = P + ((size_t)task * 16 + qi) * 28;
    pr[0] = m;
    pr[1] = l;
#pragma unroll
    for (int d = 0; d < 24; ++d) pr[2 + d] = ov[d];
  }
}

__global__ __launch_bounds__(192) void attn_merge(
    const float* __restrict__ P, unsigned short* __restrict__ o) {
  const int n = blockIdx.x;            // 0..4095
  const int tid = threadIdx.x;
  const int h = tid / 24, d = tid - h * 24;
  const int b = n >> 10, qpos = n & 1023;
  const int qg = qpos >> 4, qi = qpos & 15;
  const int g8 = qg >> 3;
  const int nch = g8 + 1;              // == qpos/128 + 1 for all qi in group
  const int bh = b * 8 + h;
  const int base = bh * 288 + 4 * g8 * (g8 + 1) + (qg - g8 * 8) * (g8 + 1);
  float M = -1e30f;
  for (int c = 0; c < nch; ++c)
    M = fmaxf(M, P[((size_t)(base + c) * 16 + qi) * 28]);
  float L = 0.0f, OV = 0.0f;
  for (int c = 0; c < nch; ++c) {
    const float* pr = P + ((size_t)(base + c) * 16 + qi) * 28;
    float w = __expf(pr[0] - M);
    L += pr[1] * w;
    OV += pr[2 + d] * w;
  }
  o[(size_t)n * 192 + h * 24 + d] = f2b(OV / L);
}

// per-row: p = dot(Dz,x)/(||Dz||+eps)^2 ; x -= p*Dz ; xb = bf16(x)
__global__ __launch_bounds__(256) void proj_update(
    const float* __restrict__ Dz, float* __restrict__ x,
    unsigned short* __restrict__ xb) {
  const int n = blockIdx.x;
  const int tid = threadIdx.x;
  const float* dz = Dz + (size_t)n * 768;
  float* xr = x + (size_t)n * 768;
  float dot = 0.0f, s2 = 0.0f;
  for (int i = tid; i < 768; i += 256) {
    float a = dz[i], c = xr[i];
    dot += a * c;
    s2 += a * a;
  }
#pragma unroll
  for (int o2 = 32; o2; o2 >>= 1) {
    dot += __shfl_down(dot, o2);
    s2 += __shfl_down(s2, o2);
  }
  __shared__ float sd[4], ss[4], sp;
  const int wave = tid >> 6, lane = tid & 63;
  if (lane == 0) { sd[wave] = dot; ss[wave] = s2; }
  __syncthreads();
  if (tid == 0) {
    float Dd = sd[0] + sd[1] + sd[2] + sd[3];
    float S = ss[0] + ss[1] + ss[2] + ss[3];
    float nrm = sqrtf(S) + 1e-6f;
    sp = Dd / (nrm * nrm);
  }
  __syncthreads();
  float p = sp;
  for (int i = tid; i < 768; i += 256) {
    float nx = xr[i] - p * dz[i];
    xr[i] = nx;
    xb[(size_t)n * 768 + i] = f2b(nx);
  }
}

DEVFN int sanitize(int v) { return (v & 0x8000) ? 0 : v; }  // -0/neg codes -> 0

// top-32 of z_novel row (bf16 codes nonneg => int order = value order);
// emits 32 (idx,val) pairs per row (slot order arbitrary).
__global__ __launch_bounds__(256) void topk_rows(
    const unsigned short* __restrict__ zbuf, int* __restrict__ idxo,
    float* __restrict__ valo) {
  const int n = blockIdx.x;
  const int b = n >> 10;
  const int tid = threadIdx.x;
  const int wave = tid >> 6, lane = tid & 63;
  const uint4v* zr = (const uint4v*)(zbuf + (size_t)(n + b + 1) * 12288);
  uint4v pk[6];
#pragma unroll
  for (int j = 0; j < 6; ++j) pk[j] = zr[tid * 6 + j];
  __shared__ int swsum[4];
  __shared__ int seq[256];
  __shared__ int spcnt;
  int lo = 0, hi = 0x7F7F;
  while (lo < hi) {
    int mid = (lo + hi) >> 1;
    int c = 0;
#pragma unroll
    for (int j = 0; j < 6; ++j)
#pragma unroll
      for (int e = 0; e < 4; ++e) {
        unsigned int u = pk[j][e];
        c += (sanitize((int)(u & 0xffffu)) > mid) + (sanitize((int)(u >> 16)) > mid);
      }
#pragma unroll
    for (int o2 = 32; o2; o2 >>= 1) c += __shfl_down(c, o2);
    if (lane == 0) swsum[wave] = c;
    __syncthreads();
    int total = swsum[0] + swsum[1] + swsum[2] + swsum[3];
    __syncthreads();
    if (total < 32) hi = mid; else lo = mid + 1;
  }
  const int T = lo;
  int cgt = 0, ceq = 0;
#pragma unroll
  for (int j = 0; j < 6; ++j)
#pragma unroll
    for (int e = 0; e < 4; ++e) {
      unsigned int u = pk[j][e];
      int v0 = sanitize((int)(u & 0xffffu)), v1 = sanitize((int)(u >> 16));
      cgt += (v0 > T) + (v1 > T);
      ceq += (v0 == T) + (v1 == T);
    }
  int cg = cgt;
#pragma unroll
  for (int o2 = 32; o2; o2 >>= 1) cg += __shfl_down(cg, o2);
  if (lane == 0) swsum[wave] = cg;
  seq[tid] = ceq;
  if (tid == 0) spcnt = 0;
  __syncthreads();
  const int total_gt = swsum[0] + swsum[1] + swsum[2] + swsum[3];
  for (int o2 = 1; o2 < 256; o2 <<= 1) {
    int vv = (tid >= o2) ? seq[tid - o2] : 0;
    __syncthreads();
    seq[tid] += vv;
    __syncthreads();
  }
  const int quota = 32 - total_gt;
  int rank = seq[tid] - ceq;
  int* irow = idxo + (size_t)n * 32;
  float* vrow = valo + (size_t)n * 32;
#pragma unroll
  for (int j = 0; j < 6; ++j)
#pragma unroll
    for (int e = 0; e < 4; ++e) {
      unsigned int u = pk[j][e];
#pragma unroll
      for (int hf = 0; hf < 2; ++hf) {
        int v = sanitize(hf ? (int)(u >> 16) : (int)(u & 0xffffu));
        bool kp = false;
        if (v > T) kp = true;
        else if (v == T) { if (rank < quota) kp = true; ++rank; }
        if (kp) {
          int pos = atomicAdd(&spcnt, 1);
          irow[pos] = tid * 48 + j * 8 + e * 2 + hf;
          vrow[pos] = b2f((unsigned short)v);
        }
      }
    }
}

// out = x_input - x_final + sum_j val_j * D[idx_j,:]   (f32 in, f32 out)
__global__ __launch_bounds__(256) void sparse_recons(
    const int* __restrict__ idxo, const float* __restrict__ valo,
    const float* __restrict__ x, const float* __restrict__ xin,
    const float* __restrict__ D, float* __restrict__ out) {
  const int n = blockIdx.x;
  const int t = threadIdx.x;
  __shared__ int sidx[32];
  __shared__ float sval[32];
  if (t < 32) { sidx[t] = idxo[(size_t)n * 32 + t]; sval[t] = valo[(size_t)n * 32 + t]; }
  __syncthreads();
  float acc[3];
#pragma unroll
  for (int u = 0; u < 3; ++u) {
    size_t i = (size_t)n * 768 + t + u * 256;
    acc[u] = xin[i] - x[i];
  }
  for (int j = 0; j < 32; ++j) {
    size_t base = (size_t)sidx[j] * 768;
    float vj = sval[j];
#pragma unroll
    for (int u = 0; u < 3; ++u) acc[u] += vj * D[base + t + u * 256];
  }
#pragma unroll
  for (int u = 0; u < 3; ++u) out[(size_t)n * 768 + t + u * 256] = acc[u];
}

// ===========================================================================
extern "C" void kernel_launch(void* const* d_in, const int* in_sizes, int n_in,
                              void* d_out, int out_size, void* d_ws, size_t ws_size,
                              hipStream_t stream) {
  (void)in_sizes; (void)n_in;
  const float* xin  = (const float*)d_in[0];
  const float* D    = (const float*)d_in[1];
  const float* bvec = (const float*)d_in[2];
  const float* Wq   = (const float*)d_in[3];
  const float* bq   = (const float*)d_in[4];
  const float* Wk   = (const float*)d_in[5];
  const float* bk   = (const float*)d_in[6];
  const float* Wv   = (const float*)d_in[7];
  const float* bv   = (const float*)d_in[8];
  const float* Wo   = (const float*)d_in[9];
  const float* bo   = (const float*)d_in[10];
  const float LAM = 1.0f / 3072.0f;

  char* ws = (char*)d_ws;
  size_t off = 0;
  auto alloc = [&](size_t bytes) {
    void* p = ws + off;
    off += (bytes + 255) & ~(size_t)255;
    return p;
  };
  unsigned short* zbuf = (unsigned short*)alloc((size_t)4 * 1025 * 12288 * 2);
  unsigned short* zpred_ = zbuf;  // alias: lifetimes disjoint
  float* attnP = (float*)zbuf;    // alias: partials live between qkv and Wo GEMMs
  float* x           = (float*)alloc((size_t)4096 * 768 * 4);
  unsigned short* xb = (unsigned short*)alloc((size_t)4096 * 768 * 2);
  float* qb  = (float*)alloc((size_t)4096 * 192 * 4);
  float* kb  = (float*)alloc((size_t)4096 * 192 * 4);
  float* vb  = (float*)alloc((size_t)4096 * 192 * 4);
  unsigned short* ob = (unsigned short*)alloc((size_t)4096 * 192 * 2);
  float* Dz  = (float*)alloc((size_t)4096 * 768 * 4);
  int* idxo  = (int*)alloc((size_t)4096 * 32 * 4);
  float* valo = (float*)alloc((size_t)4096 * 32 * 4);
  const size_t WQKV = (size_t)192 * 12288;   // per (layer, weight)
  unsigned short* WqkvT = (unsigned short*)alloc((size_t)6 * WQKV * 2);
  unsigned short* WoT   = (unsigned short*)alloc((size_t)2 * 12288 * 192 * 2);
  unsigned short* Dbt   = (unsigned short*)alloc((size_t)12288 * 768 * 2);
  unsigned short* Dt    = (unsigned short*)alloc((size_t)768 * 12288 * 2);
  const size_t NEED = off;  // ~219.8 MB (confirmed fitting in R5/R6)

  if (ws_size < NEED) {  // safety net (should never fire)
    fill_out_zero<<<(out_size + 255) / 256, 256, 0, stream>>>((float*)d_out, out_size);
    return;
  }

  init_x<<<12288, 256, 0, stream>>>(xin, bvec, x, xb);
  conv_f2b<<<9216, 256, 0, stream>>>(D, Dbt);
  transpose_f2b<<<dim3(384, 24), 256, 0, stream>>>(D, Dt, 12288, 768);
  for (int l = 0; l < 2; ++l) {
    transpose_f2b<<<dim3(384, 6), 256, 0, stream>>>(
        Wq + (size_t)l * 12288 * 192, WqkvT + (size_t)(l * 3 + 0) * WQKV, 12288, 192);
    transpose_f2b<<<dim3(384, 6), 256, 0, stream>>>(
        Wk + (size_t)l * 12288 * 192, WqkvT + (size_t)(l * 3 + 1) * WQKV, 12288, 192);
    transpose_f2b<<<dim3(384, 6), 256, 0, stream>>>(
        Wv + (size_t)l * 12288 * 192, WqkvT + (size_t)(l * 3 + 2) * WQKV, 12288, 192);
    transpose_f2b<<<dim3(6, 384), 256, 0, stream>>>(
        Wo + (size_t)l * 192 * 12288, WoT + (size_t)l * 12288 * 192, 192, 12288);
  }

  for (int l = 0; l < 2; ++l) {
    // z_in = relu(LAM * x @ D^T) -> zbuf shifted rows [b*1025+1 ..]
    gemm_bt2<unsigned short, true, 1, false, false><<<dim3(32, 96), 256, 0, stream>>>(
        xb, Dbt, zbuf, nullptr, 768, 12288, LAM);
    // q/k/v from the SAME z_in view; k/v stored row-shifted (z_ctx shift).
    // Bias prefill doubles as the zero-context row (in-batch row 0) for k/v.
    fill_bias<<<3072, 256, 0, stream>>>(qb, bq + (size_t)l * 192, 192);
    fill_bias<<<3072, 256, 0, stream>>>(kb, bk + (size_t)l * 192, 192);
    fill_bias<<<3072, 256, 0, stream>>>(vb, bv + (size_t)l * 192, 192);
    // fused q/k/v GEMM: blockIdx.z selects weight/output/shift (3 blocks/CU
    // instead of 3 serial 1-block/CU dispatches; A-tiles get 3x L2 reuse)
    gemm_qkv<<<dim3(32, 8, 3), 256, 0, stream>>>(
        zbuf, WqkvT + (size_t)(l * 3) * WQKV, qb, kb, vb);
    // Attention (z_in in zbuf is dead now; attnP scratch aliases it)
    attn_pass1<<<2304, 256, 0, stream>>>(qb, kb, vb, attnP);
    attn_merge<<<4096, 192, 0, stream>>>(attnP, ob);
    // z_pred_ = relu(o @ Wo + bo) -> zpred_ (aliases zbuf; attnP dead)
    gemm_bt2<unsigned short, true, 0, true, false><<<dim3(32, 96), 256, 0, stream>>>(
        ob, WoT + (size_t)l * 12288 * 192, zpred_, bo + (size_t)l * 12288, 192, 12288, 1.0f);
    // Dz = z_pred_ @ D  (split-K=4 -> 768 blocks = 3 blocks/CU; was split-K=2
    // at 1.5 blocks/CU which left the K-loop latency fully exposed)
    fill_bias<<<12288, 256, 0, stream>>>(Dz, nullptr, 768);
    gemm_bt2<float, false, 0, false, true><<<dim3(32, 6, 4), 256, 0, stream>>>(
        zpred_, Dt, Dz, nullptr, 12288, 768, 1.0f);
    proj_update<<<4096, 256, 0, stream>>>(Dz, x, xb);
  }
  // z_novel = relu(LAM * x @ D^T) -> zbuf shifted rows
  gemm_bt2<unsigned short, true, 1, false, false><<<dim3(32, 96), 256, 0, stream>>>(
      xb, Dbt, zbuf, nullptr, 768, 12288, LAM);
  topk_rows<<<4096, 256, 0, stream>>>(zbuf, idxo, valo);
  sparse_recons<<<4096, 256, 0, stream>>>(idxo, valo, x, xin, D, (float*)d_out);
}

// Round 2
// 1646.778 us; speedup vs baseline: 1.0519x; 1.0089x over previous
//
#include <hip/hip_runtime.h>
#include <hip/hip_bf16.h>

typedef __attribute__((ext_vector_type(4))) float f32x4;
typedef __attribute__((ext_vector_type(8))) short short8;
typedef __attribute__((ext_vector_type(8))) unsigned short ushort8;
typedef __attribute__((ext_vector_type(4))) unsigned short ushort4v;
typedef __attribute__((ext_vector_type(4))) unsigned int uint4v;

#define DEVFN __device__ __forceinline__

DEVFN float b2f(unsigned short u) { return __uint_as_float(((unsigned)u) << 16); }
DEVFN unsigned short f2b(float f) {
  __hip_bfloat16 h = __float2bfloat16(f);
  return __builtin_bit_cast(unsigned short, h);
}

DEVFN void load_lds16(const void* g, void* l) {
  __builtin_amdgcn_global_load_lds(
      (const __attribute__((address_space(1))) unsigned int*)g,
      (__attribute__((address_space(3))) unsigned int*)l, 16, 0, 0);
}

// ===========================================================================

__global__ void fill_out_zero(float* o, int n) {
  int i = blockIdx.x * 256 + threadIdx.x;
  if (i < n) o[i] = 0.0f;
}

__global__ __launch_bounds__(256) void init_x(
    const float* __restrict__ xin, const float* __restrict__ bvec,
    float* __restrict__ x, unsigned short* __restrict__ xb) {
  size_t i = (size_t)blockIdx.x * 256 + threadIdx.x;
  int col = (int)(i % 768);
  float v = xin[i] - bvec[col];
  x[i] = v;
  xb[i] = f2b(v);
}

// buf[i] = bias[i % ld] (or 0 if bias null)
__global__ __launch_bounds__(256) void fill_bias(
    float* __restrict__ buf, const float* __restrict__ bias, int ld) {
  size_t i = (size_t)blockIdx.x * 256 + threadIdx.x;
  buf[i] = bias ? bias[(int)(i % ld)] : 0.0f;
}

// f32 -> bf16 straight convert, 4 elems/thread (n must be /1024)
__global__ __launch_bounds__(256) void conv_f2b(
    const float* __restrict__ in, unsigned short* __restrict__ out) {
  size_t i = ((size_t)blockIdx.x * 256 + threadIdx.x) * 4;
  f32x4 v = *(const f32x4*)(in + i);
  ushort4v w;
#pragma unroll
  for (int e = 0; e < 4; ++e) w[e] = f2b(v[e]);
  *(ushort4v*)(out + i) = w;
}

// out[c][r] = bf16(in[r][c]); R,C multiples of 32; grid (R/32, C/32)
__global__ __launch_bounds__(256) void transpose_f2b(
    const float* __restrict__ in, unsigned short* __restrict__ out,
    int R, int C) {
  __shared__ float tile[32][33];
  int r0 = blockIdx.x * 32, c0 = blockIdx.y * 32;
  int tx = threadIdx.x & 31, ty = threadIdx.x >> 5;
#pragma unroll
  for (int i = 0; i < 4; ++i)
    tile[ty + i * 8][tx] = in[(size_t)(r0 + ty + i * 8) * C + c0 + tx];
  __syncthreads();
#pragma unroll
  for (int i = 0; i < 4; ++i)
    out[(size_t)(c0 + ty + i * 8) * R + r0 + tx] = f2b(tile[tx][ty + i * 8]);
}

// ---------------------------------------------------------------------------
// XCD-rectangle decode: 1-D launch of GX * GY * GZ blocks. bid&7 picks an
// XCD-rectangle (assumes round-robin bid%8 -> XCD; if wrong, perf-neutral).
// Rectangle = RX row-blocks x RG group-ids (g = y + GY*z), g varies fastest
// so an XCD's co-resident blocks share B-slices (L2-resident) and sweep each
// A-slice with adjacent bids (single L3 fetch, multi-use from L2).
// ---------------------------------------------------------------------------
template <int GX, int GY, int GZ, int RX, int RG>
DEVFN void rect_decode(int bid, int& x, int& y, int& z) {
  constexpr int NRG = (GY * GZ) / RG;   // rectangles along g
  const int xcd = bid & 7;
  const int rr = bid >> 3;              // [0, RX*RG)
  const int rgx = xcd % NRG, rxx = xcd / NRG;
  const int gl = rr % RG, xl = rr / RG;
  const int g = rgx * RG + gl;
  x = rxx * RX + xl;
  y = g % GY;
  z = g / GY;
}

// ---------------------------------------------------------------------------
// gemm_bt2: C[M,N] = epi(alpha * A[M,K] . B[N,K]^T + bias)  both bf16 K-major.
// 128x128 tile, BK=64, global_load_lds staging (conflict-free).
// SC=1: C rows shifted per batch (z storage [b][1+1024][W]).
// 1-D grid of GX*GY*GZ blocks, XCD-rectangle scheduled.
// ---------------------------------------------------------------------------
template <typename CT, bool RELU, int SC, bool BIAS, bool SPLITK,
          int GX, int GY, int GZ, int RX, int RG>
__global__ __launch_bounds__(256) void gemm_bt2(
    const unsigned short* __restrict__ A, const unsigned short* __restrict__ B,
    CT* __restrict__ C, const float* __restrict__ bias,
    int K, int ldc, float alpha) {
  __shared__ unsigned short sA[128 * 64];
  __shared__ unsigned short sB[128 * 64];
  const int tid = threadIdx.x;
  const int wave = tid >> 6, lane = tid & 63;
  int bx, by, bz;
  rect_decode<GX, GY, GZ, RX, RG>((int)blockIdx.x, bx, by, bz);
  const int row0 = bx * 128, col0 = by * 128;
  const unsigned short* Ab = A + (size_t)row0 * K;
  const unsigned short* Bb = B + (size_t)col0 * K;
  const int srow = lane >> 3;
  const int scol = (lane & 7) * 8;
  const int wm = wave & 1, wn = wave >> 1;
  const int lr = lane & 15;
  const int lk = (lane >> 4) * 8;
  const int klen = SPLITK ? (K / GZ) : K;
  const int kbeg = SPLITK ? bz * klen : 0;
  f32x4 acc[4][4] = {};
  for (int k0 = kbeg; k0 < kbeg + klen; k0 += 64) {
#pragma unroll
    for (int it = 0; it < 4; ++it) {
      int chunk = wave * 4 + it;
      int r = chunk * 8 + srow;
      load_lds16(Ab + (size_t)r * K + k0 + scol, &sA[chunk * 512]);
      load_lds16(Bb + (size_t)r * K + k0 + scol, &sB[chunk * 512]);
    }
    __syncthreads();
#pragma unroll
    for (int ks = 0; ks < 2; ++ks) {
      short8 af[4], bfr[4];
#pragma unroll
      for (int i = 0; i < 4; ++i)
        af[i] = *(const short8*)&sA[(wm * 64 + i * 16 + lr) * 64 + ks * 32 + lk];
#pragma unroll
      for (int i = 0; i < 4; ++i)
        bfr[i] = *(const short8*)&sB[(wn * 64 + i * 16 + lr) * 64 + ks * 32 + lk];
#pragma unroll
      for (int i = 0; i < 4; ++i)
#pragma unroll
        for (int j = 0; j < 4; ++j)
          acc[i][j] = __builtin_amdgcn_mfma_f32_16x16x32_bf16(af[i], bfr[j], acc[i][j], 0, 0, 0);
    }
    __syncthreads();
  }
  const int rc = (SC == 0) ? 0 : ((row0 >> 10) + 1);
  const int rbase = row0 + rc + wm * 64 + (lane >> 4) * 4;
  const int cbase = col0 + wn * 64 + lr;
#pragma unroll
  for (int j = 0; j < 4; ++j) {
    int col = cbase + j * 16;
    float bv = BIAS ? bias[col] : 0.0f;
#pragma unroll
    for (int i = 0; i < 4; ++i) {
#pragma unroll
      for (int r = 0; r < 4; ++r) {
        float vv = acc[i][j][r] * alpha;
        size_t off = (size_t)(rbase + i * 16 + r) * ldc + col;
        if constexpr (SPLITK) {
          atomicAdd((float*)C + off, vv);
        } else {
          vv += bv;
          if (RELU) vv = fmaxf(vv, 0.0f);
          if constexpr (sizeof(CT) == 2) ((unsigned short*)C)[off] = f2b(vv);
          else C[off] = vv;
        }
      }
    }
  }
}

// ---------------------------------------------------------------------------
// gemm_qkv: fused q/k/v projection, 1-D grid of 768 blocks.
// Logical coords (x: 32 row-blocks, y: 8 k-splits, z: 3 weights).
// XCD-rectangle: 8x x (4y x 3z), g = z + 3*y with z fastest (A k-window
// reused across the 3 weights from L2; B (y,z)-slices L2-resident per XCD).
// C[4096,192] (f32, atomic) += A_zin . B_wz[192,12288]^T
// BM=128, BN=192, BK=64, waves 2x2 (64x96 each).
// k/v (z>0): store row t -> t+1 within batch, dropping in-batch row 1023.
// ---------------------------------------------------------------------------
__global__ __launch_bounds__(256) void gemm_qkv(
    const unsigned short* __restrict__ A, const unsigned short* __restrict__ Bq,
    float* __restrict__ qb, float* __restrict__ kb, float* __restrict__ vb) {
  __shared__ unsigned short sA[128 * 64];   // 16 KB
  __shared__ unsigned short sB[192 * 64];   // 24 KB
  const int tid = threadIdx.x;
  const int wave = tid >> 6, lane = tid & 63;
  // rectangle decode: 8 rects = 4(x) x 2(g); rect = 8x x 12g; g = z + 3*y
  const int bid = (int)blockIdx.x;
  const int xcd = bid & 7;
  const int rr = bid >> 3;                  // [0,96)
  const int rgx = xcd % 2, rxx = xcd / 2;   // g-half, x-quarter
  const int gl = rr % 12, xl = rr / 12;     // g fastest
  const int g = rgx * 12 + gl;              // [0,24)
  const int bx = rxx * 8 + xl;              // [0,32)
  const int wz = g % 3;                     // weight: 0=q,1=k,2=v
  const int ky = g / 3;                     // k-split [0,8)
  const int shift = (wz > 0);
  const unsigned short* B = Bq + (size_t)wz * 192 * 12288;
  float* C = (wz == 0) ? qb : (wz == 1 ? kb : vb);
  const int row0 = bx * 128;
  const int ra = (row0 >> 10) + 1;          // z_in view
  const unsigned short* Ab = A + (size_t)(row0 + ra) * 12288;
  const int srow = lane >> 3;
  const int scol = (lane & 7) * 8;
  const int wm = wave & 1, wn = wave >> 1;
  const int lr = lane & 15;
  const int lk = (lane >> 4) * 8;
  const int kbeg = ky * 1536;               // 12288/8
  f32x4 acc[4][6] = {};
  for (int k0 = kbeg; k0 < kbeg + 1536; k0 += 64) {
    // 40 chunks of 8 rows: 0..15 = A, 16..39 = B; 10 per wave
#pragma unroll
    for (int it = 0; it < 10; ++it) {
      int c = wave * 10 + it;
      if (c < 16) {
        int r = c * 8 + srow;
        load_lds16(Ab + (size_t)r * 12288 + k0 + scol, &sA[c * 512]);
      } else {
        int cb = c - 16;
        int r = cb * 8 + srow;
        load_lds16(B + (size_t)r * 12288 + k0 + scol, &sB[cb * 512]);
      }
    }
    __syncthreads();
#pragma unroll
    for (int ks = 0; ks < 2; ++ks) {
      short8 af[4], bfr[6];
#pragma unroll
      for (int i = 0; i < 4; ++i)
        af[i] = *(const short8*)&sA[(wm * 64 + i * 16 + lr) * 64 + ks * 32 + lk];
#pragma unroll
      for (int j = 0; j < 6; ++j)
        bfr[j] = *(const short8*)&sB[(wn * 96 + j * 16 + lr) * 64 + ks * 32 + lk];
#pragma unroll
      for (int i = 0; i < 4; ++i)
#pragma unroll
        for (int j = 0; j < 6; ++j)
          acc[i][j] = __builtin_amdgcn_mfma_f32_16x16x32_bf16(af[i], bfr[j], acc[i][j], 0, 0, 0);
    }
    __syncthreads();
  }
  const int rbase = row0 + wm * 64 + (lane >> 4) * 4;
  const int cbase = wn * 96 + lr;
#pragma unroll
  for (int j = 0; j < 6; ++j) {
    int col = cbase + j * 16;
#pragma unroll
    for (int i = 0; i < 4; ++i)
#pragma unroll
      for (int r = 0; r < 4; ++r) {
        int rw = rbase + i * 16 + r;
        if (shift) {
          if ((rw & 1023) == 1023) continue;  // dropped (next batch's row 0 = bias)
          rw += 1;
        }
        atomicAdd(C + (size_t)rw * 192 + col, acc[i][j][r]);
      }
  }
}

// ---------------------------------------------------------------------------
// Attention, two-pass flash-decode.
// ---------------------------------------------------------------------------
__global__ __launch_bounds__(256) void attn_pass1(
    const float* __restrict__ q, const float* __restrict__ k,
    const float* __restrict__ v, float* __restrict__ P) {
  const int wave = threadIdx.x >> 6, lane = threadIdx.x & 63;
  const int task = (int)blockIdx.x * 4 + wave;  // 0..9215
  const int bh = task / 288, t = task % 288;
  const int b = bh >> 3, h = bh & 7;
  int g8 = 0;
  while (4 * (g8 + 1) * (g8 + 2) <= t) ++g8;
  const int r = t - 4 * g8 * (g8 + 1);
  const int qg = g8 * 8 + r / (g8 + 1);
  const int chunk = r % (g8 + 1);
  const int qi = lane & 15, ks = lane >> 4;
  const int qpos = qg * 16 + qi;
  const int n = b * 1024 + qpos;
  const float scale = 0.20412414523193154f;  // 1/sqrt(24)
  float qv[24];
  const float* qr = q + (size_t)n * 192 + h * 24;
#pragma unroll
  for (int d = 0; d < 24; ++d) qv[d] = qr[d] * scale;
  float m = -1e30f, l = 0.0f, ov[24] = {};
  const float* kbp = k + (size_t)b * 1024 * 192 + h * 24;
  const float* vbp = v + (size_t)b * 1024 * 192 + h * 24;
  const int kend = min(qpos, chunk * 128 + 127);
  for (int kp = chunk * 128 + ks; kp <= kend; kp += 4) {
    const f32x4* kr = (const f32x4*)(kbp + (size_t)kp * 192);
    float s0 = 0.0f, s1 = 0.0f, s2 = 0.0f;
#pragma unroll
    for (int j = 0; j < 2; ++j) {
      f32x4 k0 = kr[j * 3 + 0], k1 = kr[j * 3 + 1], k2 = kr[j * 3 + 2];
#pragma unroll
      for (int e = 0; e < 4; ++e) {
        s0 += qv[(j * 3 + 0) * 4 + e] * k0[e];
        s1 += qv[(j * 3 + 1) * 4 + e] * k1[e];
        s2 += qv[(j * 3 + 2) * 4 + e] * k2[e];
      }
    }
    float s = s0 + s1 + s2;
    float mn = fmaxf(m, s);
    float corr = __expf(m - mn);
    float p = __expf(s - mn);
    const f32x4* vr = (const f32x4*)(vbp + (size_t)kp * 192);
    l = l * corr + p;
#pragma unroll
    for (int j = 0; j < 6; ++j) {
      f32x4 vvv = vr[j];
#pragma unroll
      for (int e = 0; e < 4; ++e) ov[j * 4 + e] = ov[j * 4 + e] * corr + p * vvv[e];
    }
    m = mn;
  }
  // merge the 4 k-slices (lanes qi, qi+16, qi+32, qi+48)
#pragma unroll
  for (int off = 16; off < 64; off <<= 1) {
    float m2 = __shfl_xor(m, off);
    float l2 = __shfl_xor(l, off);
    float mn = fmaxf(m, m2);
    float c1 = __expf(m - mn), c2 = __expf(m2 - mn);
    l = l * c1 + l2 * c2;
#pragma unroll
    for (int d = 0; d < 24; ++d) {
      float o2 = __shfl_xor(ov[d], off);
      ov[d] = ov[d] * c1 + o2 * c2;
    }
    m = mn;
  }
  if (ks == 0) {
    float* pr = P + ((size_t)task * 16 + qi) * 28;
    pr[0] = m;
    pr[1] = l;
#pragma unroll
    for (int d = 0; d < 24; ++d) pr[2 + d] = ov[d];
  }
}

__global__ __launch_bounds__(192) void attn_merge(
    const float* __restrict__ P, unsigned short* __restrict__ o) {
  const int n = blockIdx.x;            // 0..4095
  const int tid = threadIdx.x;
  const int h = tid / 24, d = tid - h * 24;
  const int b = n >> 10, qpos = n & 1023;
  const int qg = qpos >> 4, qi = qpos & 15;
  const int g8 = qg >> 3;
  const int nch = g8 + 1;              // == qpos/128 + 1 for all qi in group
  const int bh = b * 8 + h;
  const int base = bh * 288 + 4 * g8 * (g8 + 1) + (qg - g8 * 8) * (g8 + 1);
  float M = -1e30f;
  for (int c = 0; c < nch; ++c)
    M = fmaxf(M, P[((size_t)(base + c) * 16 + qi) * 28]);
  float L = 0.0f, OV = 0.0f;
  for (int c = 0; c < nch; ++c) {
    const float* pr = P + ((size_t)(base + c) * 16 + qi) * 28;
    float w = __expf(pr[0] - M);
    L += pr[1] * w;
    OV += pr[2 + d] * w;
  }
  o[(size_t)n * 192 + h * 24 + d] = f2b(OV / L);
}

// per-row: p = dot(Dz,x)/(||Dz||+eps)^2 ; x -= p*Dz ; xb = bf16(x)
__global__ __launch_bounds__(256) void proj_update(
    const float* __restrict__ Dz, float* __restrict__ x,
    unsigned short* __restrict__ xb) {
  const int n = blockIdx.x;
  const int tid = threadIdx.x;
  const float* dz = Dz + (size_t)n * 768;
  float* xr = x + (size_t)n * 768;
  float dot = 0.0f, s2 = 0.0f;
  for (int i = tid; i < 768; i += 256) {
    float a = dz[i], c = xr[i];
    dot += a * c;
    s2 += a * a;
  }
#pragma unroll
  for (int o2 = 32; o2; o2 >>= 1) {
    dot += __shfl_down(dot, o2);
    s2 += __shfl_down(s2, o2);
  }
  __shared__ float sd[4], ss[4], sp;
  const int wave = tid >> 6, lane = tid & 63;
  if (lane == 0) { sd[wave] = dot; ss[wave] = s2; }
  __syncthreads();
  if (tid == 0) {
    float Dd = sd[0] + sd[1] + sd[2] + sd[3];
    float S = ss[0] + ss[1] + ss[2] + ss[3];
    float nrm = sqrtf(S) + 1e-6f;
    sp = Dd / (nrm * nrm);
  }
  __syncthreads();
  float p = sp;
  for (int i = tid; i < 768; i += 256) {
    float nx = xr[i] - p * dz[i];
    xr[i] = nx;
    xb[(size_t)n * 768 + i] = f2b(nx);
  }
}

DEVFN int sanitize(int v) { return (v & 0x8000) ? 0 : v; }  // -0/neg codes -> 0

// top-32 of z_novel row (bf16 codes nonneg => int order = value order);
// emits 32 (idx,val) pairs per row (slot order arbitrary).
__global__ __launch_bounds__(256) void topk_rows(
    const unsigned short* __restrict__ zbuf, int* __restrict__ idxo,
    float* __restrict__ valo) {
  const int n = blockIdx.x;
  const int b = n >> 10;
  const int tid = threadIdx.x;
  const int wave = tid >> 6, lane = tid & 63;
  const uint4v* zr = (const uint4v*)(zbuf + (size_t)(n + b + 1) * 12288);
  uint4v pk[6];
#pragma unroll
  for (int j = 0; j < 6; ++j) pk[j] = zr[tid * 6 + j];
  __shared__ int swsum[4];
  __shared__ int seq[256];
  __shared__ int spcnt;
  int lo = 0, hi = 0x7F7F;
  while (lo < hi) {
    int mid = (lo + hi) >> 1;
    int c = 0;
#pragma unroll
    for (int j = 0; j < 6; ++j)
#pragma unroll
      for (int e = 0; e < 4; ++e) {
        unsigned int u = pk[j][e];
        c += (sanitize((int)(u & 0xffffu)) > mid) + (sanitize((int)(u >> 16)) > mid);
      }
#pragma unroll
    for (int o2 = 32; o2; o2 >>= 1) c += __shfl_down(c, o2);
    if (lane == 0) swsum[wave] = c;
    __syncthreads();
    int total = swsum[0] + swsum[1] + swsum[2] + swsum[3];
    __syncthreads();
    if (total < 32) hi = mid; else lo = mid + 1;
  }
  const int T = lo;
  int cgt = 0, ceq = 0;
#pragma unroll
  for (int j = 0; j < 6; ++j)
#pragma unroll
    for (int e = 0; e < 4; ++e) {
      unsigned int u = pk[j][e];
      int v0 = sanitize((int)(u & 0xffffu)), v1 = sanitize((int)(u >> 16));
      cgt += (v0 > T) + (v1 > T);
      ceq += (v0 == T) + (v1 == T);
    }
  int cg = cgt;
#pragma unroll
  for (int o2 = 32; o2; o2 >>= 1) cg += __shfl_down(cg, o2);
  if (lane == 0) swsum[wave] = cg;
  seq[tid] = ceq;
  if (tid == 0) spcnt = 0;
  __syncthreads();
  const int total_gt = swsum[0] + swsum[1] + swsum[2] + swsum[3];
  for (int o2 = 1; o2 < 256; o2 <<= 1) {
    int vv = (tid >= o2) ? seq[tid - o2] : 0;
    __syncthreads();
    seq[tid] += vv;
    __syncthreads();
  }
  const int quota = 32 - total_gt;
  int rank = seq[tid] - ceq;
  int* irow = idxo + (size_t)n * 32;
  float* vrow = valo + (size_t)n * 32;
#pragma unroll
  for (int j = 0; j < 6; ++j)
#pragma unroll
    for (int e = 0; e < 4; ++e) {
      unsigned int u = pk[j][e];
#pragma unroll
      for (int hf = 0; hf < 2; ++hf) {
        int v = sanitize(hf ? (int)(u >> 16) : (int)(u & 0xffffu));
        bool kp = false;
        if (v > T) kp = true;
        else if (v == T) { if (rank < quota) kp = true; ++rank; }
        if (kp) {
          int pos = atomicAdd(&spcnt, 1);
          irow[pos] = tid * 48 + j * 8 + e * 2 + hf;
          vrow[pos] = b2f((unsigned short)v);
        }
      }
    }
}

// out = x_input - x_final + sum_j val_j * D[idx_j,:]   (f32 in, f32 out)
__global__ __launch_bounds__(256) void sparse_recons(
    const int* __restrict__ idxo, const float* __restrict__ valo,
    const float* __restrict__ x, const float* __restrict__ xin,
    const float* __restrict__ D, float* __restrict__ out) {
  const int n = blockIdx.x;
  const int t = threadIdx.x;
  __shared__ int sidx[32];
  __shared__ float sval[32];
  if (t < 32) { sidx[t] = idxo[(size_t)n * 32 + t]; sval[t] = valo[(size_t)n * 32 + t]; }
  __syncthreads();
  float acc[3];
#pragma unroll
  for (int u = 0; u < 3; ++u) {
    size_t i = (size_t)n * 768 + t + u * 256;
    acc[u] = xin[i] - x[i];
  }
  for (int j = 0; j < 32; ++j) {
    size_t base = (size_t)sidx[j] * 768;
    float vj = sval[j];
#pragma unroll
    for (int u = 0; u < 3; ++u) acc[u] += vj * D[base + t + u * 256];
  }
#pragma unroll
  for (int u = 0; u < 3; ++u) out[(size_t)n * 768 + t + u * 256] = acc[u];
}

// ===========================================================================
extern "C" void kernel_launch(void* const* d_in, const int* in_sizes, int n_in,
                              void* d_out, int out_size, void* d_ws, size_t ws_size,
                              hipStream_t stream) {
  (void)in_sizes; (void)n_in;
  const float* xin  = (const float*)d_in[0];
  const float* D    = (const float*)d_in[1];
  const float* bvec = (const float*)d_in[2];
  const float* Wq   = (const float*)d_in[3];
  const float* bq   = (const float*)d_in[4];
  const float* Wk   = (const float*)d_in[5];
  const float* bk   = (const float*)d_in[6];
  const float* Wv   = (const float*)d_in[7];
  const float* bv   = (const float*)d_in[8];
  const float* Wo   = (const float*)d_in[9];
  const float* bo   = (const float*)d_in[10];
  const float LAM = 1.0f / 3072.0f;

  char* ws = (char*)d_ws;
  size_t off = 0;
  auto alloc = [&](size_t bytes) {
    void* p = ws + off;
    off += (bytes + 255) & ~(size_t)255;
    return p;
  };
  unsigned short* zbuf = (unsigned short*)alloc((size_t)4 * 1025 * 12288 * 2);
  unsigned short* zpred_ = zbuf;  // alias: lifetimes disjoint
  float* attnP = (float*)zbuf;    // alias: partials live between qkv and Wo GEMMs
  float* x           = (float*)alloc((size_t)4096 * 768 * 4);
  unsigned short* xb = (unsigned short*)alloc((size_t)4096 * 768 * 2);
  float* qb  = (float*)alloc((size_t)4096 * 192 * 4);
  float* kb  = (float*)alloc((size_t)4096 * 192 * 4);
  float* vb  = (float*)alloc((size_t)4096 * 192 * 4);
  unsigned short* ob = (unsigned short*)alloc((size_t)4096 * 192 * 2);
  float* Dz  = (float*)alloc((size_t)4096 * 768 * 4);
  int* idxo  = (int*)alloc((size_t)4096 * 32 * 4);
  float* valo = (float*)alloc((size_t)4096 * 32 * 4);
  const size_t WQKV = (size_t)192 * 12288;   // per (layer, weight)
  unsigned short* WqkvT = (unsigned short*)alloc((size_t)6 * WQKV * 2);
  unsigned short* WoT   = (unsigned short*)alloc((size_t)2 * 12288 * 192 * 2);
  unsigned short* Dbt   = (unsigned short*)alloc((size_t)12288 * 768 * 2);
  unsigned short* Dt    = (unsigned short*)alloc((size_t)768 * 12288 * 2);
  const size_t NEED = off;  // ~219.8 MB (confirmed fitting in R5/R6)

  if (ws_size < NEED) {  // safety net (should never fire)
    fill_out_zero<<<(out_size + 255) / 256, 256, 0, stream>>>((float*)d_out, out_size);
    return;
  }

  init_x<<<12288, 256, 0, stream>>>(xin, bvec, x, xb);
  conv_f2b<<<9216, 256, 0, stream>>>(D, Dbt);
  transpose_f2b<<<dim3(384, 24), 256, 0, stream>>>(D, Dt, 12288, 768);
  for (int l = 0; l < 2; ++l) {
    transpose_f2b<<<dim3(384, 6), 256, 0, stream>>>(
        Wq + (size_t)l * 12288 * 192, WqkvT + (size_t)(l * 3 + 0) * WQKV, 12288, 192);
    transpose_f2b<<<dim3(384, 6), 256, 0, stream>>>(
        Wk + (size_t)l * 12288 * 192, WqkvT + (size_t)(l * 3 + 1) * WQKV, 12288, 192);
    transpose_f2b<<<dim3(384, 6), 256, 0, stream>>>(
        Wv + (size_t)l * 12288 * 192, WqkvT + (size_t)(l * 3 + 2) * WQKV, 12288, 192);
    transpose_f2b<<<dim3(6, 384), 256, 0, stream>>>(
        Wo + (size_t)l * 192 * 12288, WoT + (size_t)l * 12288 * 192, 192, 12288);
  }

  for (int l = 0; l < 2; ++l) {
    // z_in = relu(LAM * x @ D^T) -> zbuf shifted rows [b*1025+1 ..]
    // grid 32x96 -> 1-D 3072, XCD-rect 16x x 24y (B-slices L2-resident)
    gemm_bt2<unsigned short, true, 1, false, false, 32, 96, 1, 16, 24>
        <<<3072, 256, 0, stream>>>(xb, Dbt, zbuf, nullptr, 768, 12288, LAM);
    // q/k/v from the SAME z_in view; k/v stored row-shifted (z_ctx shift).
    // Bias prefill doubles as the zero-context row (in-batch row 0) for k/v.
    fill_bias<<<3072, 256, 0, stream>>>(qb, bq + (size_t)l * 192, 192);
    fill_bias<<<3072, 256, 0, stream>>>(kb, bk + (size_t)l * 192, 192);
    fill_bias<<<3072, 256, 0, stream>>>(vb, bv + (size_t)l * 192, 192);
    // fused q/k/v GEMM, 1-D 768 blocks, XCD-rect 8x x (4y x 3z)
    gemm_qkv<<<768, 256, 0, stream>>>(
        zbuf, WqkvT + (size_t)(l * 3) * WQKV, qb, kb, vb);
    // Attention (z_in in zbuf is dead now; attnP scratch aliases it)
    attn_pass1<<<2304, 256, 0, stream>>>(qb, kb, vb, attnP);
    attn_merge<<<4096, 192, 0, stream>>>(attnP, ob);
    // z_pred_ = relu(o @ Wo + bo) -> zpred_ (aliases zbuf; attnP dead)
    gemm_bt2<unsigned short, true, 0, true, false, 32, 96, 1, 16, 24>
        <<<3072, 256, 0, stream>>>(
        ob, WoT + (size_t)l * 12288 * 192, zpred_, bo + (size_t)l * 12288, 192, 12288, 1.0f);
    // Dz = z_pred_ @ D  (split-K=4, atomic into zero-prefilled f32)
    // 1-D 768 blocks, XCD-rect 16x x (6y x 1z): each XCD owns one k-split
    // half; B k-window slices stay L2-resident, A swept once per XCD.
    fill_bias<<<12288, 256, 0, stream>>>(Dz, nullptr, 768);
    gemm_bt2<float, false, 0, false, true, 32, 6, 4, 16, 6>
        <<<768, 256, 0, stream>>>(zpred_, Dt, Dz, nullptr, 12288, 768, 1.0f);
    proj_update<<<4096, 256, 0, stream>>>(Dz, x, xb);
  }
  // z_novel = relu(LAM * x @ D^T) -> zbuf shifted rows
  gemm_bt2<unsigned short, true, 1, false, false, 32, 96, 1, 16, 24>
      <<<3072, 256, 0, stream>>>(xb, Dbt, zbuf, nullptr, 768, 12288, LAM);
  topk_rows<<<4096, 256, 0, stream>>>(zbuf, idxo, valo);
  sparse_recons<<<4096, 256, 0, stream>>>(idxo, valo, x, xin, D, (float*)d_out);
}

// Round 3
// 1479.161 us; speedup vs baseline: 1.1711x; 1.1133x over previous
//
#include <hip/hip_runtime.h>
#include <hip/hip_bf16.h>

typedef __attribute__((ext_vector_type(4))) float f32x4;
typedef __attribute__((ext_vector_type(8))) short short8;
typedef __attribute__((ext_vector_type(8))) unsigned short ushort8;
typedef __attribute__((ext_vector_type(4))) unsigned short ushort4v;
typedef __attribute__((ext_vector_type(4))) unsigned int uint4v;

#define DEVFN __device__ __forceinline__

DEVFN float b2f(unsigned short u) { return __uint_as_float(((unsigned)u) << 16); }
DEVFN unsigned short f2b(float f) {
  __hip_bfloat16 h = __float2bfloat16(f);
  return __builtin_bit_cast(unsigned short, h);
}

DEVFN void load_lds16(const void* g, void* l) {
  __builtin_amdgcn_global_load_lds(
      (const __attribute__((address_space(1))) unsigned int*)g,
      (__attribute__((address_space(3))) unsigned int*)l, 16, 0, 0);
}

// ===========================================================================

__global__ void fill_out_zero(float* o, int n) {
  int i = blockIdx.x * 256 + threadIdx.x;
  if (i < n) o[i] = 0.0f;
}

__global__ __launch_bounds__(256) void init_x(
    const float* __restrict__ xin, const float* __restrict__ bvec,
    float* __restrict__ x, unsigned short* __restrict__ xb) {
  size_t i = (size_t)blockIdx.x * 256 + threadIdx.x;
  int col = (int)(i % 768);
  float v = xin[i] - bvec[col];
  x[i] = v;
  xb[i] = f2b(v);
}

// buf[i] = bias[i % ld] (or 0 if bias null)
__global__ __launch_bounds__(256) void fill_bias(
    float* __restrict__ buf, const float* __restrict__ bias, int ld) {
  size_t i = (size_t)blockIdx.x * 256 + threadIdx.x;
  buf[i] = bias ? bias[(int)(i % ld)] : 0.0f;
}

// f32 -> bf16 straight convert, 4 elems/thread (n must be /1024)
__global__ __launch_bounds__(256) void conv_f2b(
    const float* __restrict__ in, unsigned short* __restrict__ out) {
  size_t i = ((size_t)blockIdx.x * 256 + threadIdx.x) * 4;
  f32x4 v = *(const f32x4*)(in + i);
  ushort4v w;
#pragma unroll
  for (int e = 0; e < 4; ++e) w[e] = f2b(v[e]);
  *(ushort4v*)(out + i) = w;
}

// out[c][r] = bf16(in[r][c]); R,C multiples of 32; grid (R/32, C/32)
__global__ __launch_bounds__(256) void transpose_f2b(
    const float* __restrict__ in, unsigned short* __restrict__ out,
    int R, int C) {
  __shared__ float tile[32][33];
  int r0 = blockIdx.x * 32, c0 = blockIdx.y * 32;
  int tx = threadIdx.x & 31, ty = threadIdx.x >> 5;
#pragma unroll
  for (int i = 0; i < 4; ++i)
    tile[ty + i * 8][tx] = in[(size_t)(r0 + ty + i * 8) * C + c0 + tx];
  __syncthreads();
#pragma unroll
  for (int i = 0; i < 4; ++i)
    out[(size_t)(c0 + ty + i * 8) * R + r0 + tx] = f2b(tile[tx][ty + i * 8]);
}

// ---------------------------------------------------------------------------
// XCD-rectangle decode: 1-D launch of GX * GY * GZ blocks. bid&7 picks an
// XCD-rectangle (assumes round-robin bid%8 -> XCD; if wrong, perf-neutral).
// Rectangle = RX row-blocks x RG group-ids (g = y + GY*z), g varies fastest.
// ---------------------------------------------------------------------------
template <int GX, int GY, int GZ, int RX, int RG>
DEVFN void rect_decode(int bid, int& x, int& y, int& z) {
  constexpr int NRG = (GY * GZ) / RG;   // rectangles along g
  const int xcd = bid & 7;
  const int rr = bid >> 3;              // [0, RX*RG)
  const int rgx = xcd % NRG, rxx = xcd / NRG;
  const int gl = rr % RG, xl = rr / RG;
  const int g = rgx * RG + gl;
  x = rxx * RX + xl;
  y = g % GY;
  z = g / GY;
}

// ---------------------------------------------------------------------------
// gemm_bt2: C[M,N] = epi(alpha * A[M,K] . B[N,K]^T + bias)  both bf16 K-major.
// 128x128 tile, BK=64, double-buffered global_load_lds staging (one barrier
// per K-iter; stage(t+1) issued BEFORE compute(t) so load latency hides under
// ds_read+MFMA). LDS XOR-swizzle: physical slot p of row r holds global
// col-block p^(r&7); staging pre-swizzles the GLOBAL source col (LDS dest
// must stay linear for global_load_lds), reads swizzle the slot index ->
// conflict-free ds_read_b128 (was 16-way, 2x read cost).
// SC=1: C rows shifted per batch (z storage [b][1+1024][W]).
// 1-D grid of GX*GY*GZ blocks, XCD-rectangle scheduled.
// ---------------------------------------------------------------------------
template <typename CT, bool RELU, int SC, bool BIAS, bool SPLITK,
          int GX, int GY, int GZ, int RX, int RG>
__global__ __launch_bounds__(256) void gemm_bt2(
    const unsigned short* __restrict__ A, const unsigned short* __restrict__ B,
    CT* __restrict__ C, const float* __restrict__ bias,
    int K, int ldc, float alpha) {
  __shared__ unsigned short sA[2][128 * 64];
  __shared__ unsigned short sB[2][128 * 64];
  const int tid = threadIdx.x;
  const int wave = tid >> 6, lane = tid & 63;
  int bx, by, bz;
  rect_decode<GX, GY, GZ, RX, RG>((int)blockIdx.x, bx, by, bz);
  const int row0 = bx * 128, col0 = by * 128;
  const unsigned short* Ab = A + (size_t)row0 * K;
  const unsigned short* Bb = B + (size_t)col0 * K;
  const int srow = lane >> 3;
  const int swc = ((lane & 7) ^ srow) * 8;       // pre-swizzled global col
  const int wm = wave & 1, wn = wave >> 1;
  const int lr = lane & 15;
  const int hi = lane >> 4;
  const int l7 = lane & 7;
  const int ksw0 = (hi ^ l7) * 8;                // swizzled LDS slot, ks=0
  const int ksw1 = ((4 + hi) ^ l7) * 8;          // swizzled LDS slot, ks=1
  const int klen = SPLITK ? (K / GZ) : K;
  const int kbeg = SPLITK ? bz * klen : 0;
  const int nt = klen / 64;
  f32x4 acc[4][4] = {};
  auto stage = [&](int buf, int t) {
    const int k0 = kbeg + t * 64;
#pragma unroll
    for (int it = 0; it < 4; ++it) {
      int chunk = wave * 4 + it;
      int r = chunk * 8 + srow;
      load_lds16(Ab + (size_t)r * K + k0 + swc, &sA[buf][chunk * 512]);
      load_lds16(Bb + (size_t)r * K + k0 + swc, &sB[buf][chunk * 512]);
    }
  };
  stage(0, 0);
  __syncthreads();
  for (int t = 0; t < nt; ++t) {
    const int cur = t & 1;
    if (t + 1 < nt) stage(cur ^ 1, t + 1);
    const unsigned short* cA = &sA[cur][0];
    const unsigned short* cB = &sB[cur][0];
#pragma unroll
    for (int ks = 0; ks < 2; ++ks) {
      const int ko = ks ? ksw1 : ksw0;
      short8 af[4], bfr[4];
#pragma unroll
      for (int i = 0; i < 4; ++i)
        af[i] = *(const short8*)&cA[(wm * 64 + i * 16 + lr) * 64 + ko];
#pragma unroll
      for (int i = 0; i < 4; ++i)
        bfr[i] = *(const short8*)&cB[(wn * 64 + i * 16 + lr) * 64 + ko];
#pragma unroll
      for (int i = 0; i < 4; ++i)
#pragma unroll
        for (int j = 0; j < 4; ++j)
          acc[i][j] = __builtin_amdgcn_mfma_f32_16x16x32_bf16(af[i], bfr[j], acc[i][j], 0, 0, 0);
    }
    __syncthreads();
  }
  const int rc = (SC == 0) ? 0 : ((row0 >> 10) + 1);
  const int rbase = row0 + rc + wm * 64 + (lane >> 4) * 4;
  const int cbase = col0 + wn * 64 + lr;
#pragma unroll
  for (int j = 0; j < 4; ++j) {
    int col = cbase + j * 16;
    float bv = BIAS ? bias[col] : 0.0f;
#pragma unroll
    for (int i = 0; i < 4; ++i) {
#pragma unroll
      for (int r = 0; r < 4; ++r) {
        float vv = acc[i][j][r] * alpha;
        size_t off = (size_t)(rbase + i * 16 + r) * ldc + col;
        if constexpr (SPLITK) {
          atomicAdd((float*)C + off, vv);
        } else {
          vv += bv;
          if (RELU) vv = fmaxf(vv, 0.0f);
          if constexpr (sizeof(CT) == 2) ((unsigned short*)C)[off] = f2b(vv);
          else C[off] = vv;
        }
      }
    }
  }
}

// ---------------------------------------------------------------------------
// gemm_qkv: fused q/k/v projection, 1-D grid of 768 blocks.
// Logical coords (x: 32 row-blocks, y: 8 k-splits, z: 3 weights).
// XCD-rectangle: 8x x (4y x 3z), g = z + 3*y with z fastest.
// Same double-buffer + swizzle scheme as gemm_bt2.
// C[4096,192] (f32, atomic) += A_zin . B_wz[192,12288]^T
// BM=128, BN=192, BK=64, waves 2x2 (64x96 each).
// k/v (z>0): store row t -> t+1 within batch, dropping in-batch row 1023.
// ---------------------------------------------------------------------------
__global__ __launch_bounds__(256) void gemm_qkv(
    const unsigned short* __restrict__ A, const unsigned short* __restrict__ Bq,
    float* __restrict__ qb, float* __restrict__ kb, float* __restrict__ vb) {
  __shared__ unsigned short sA[2][128 * 64];   // 32 KB
  __shared__ unsigned short sB[2][192 * 64];   // 48 KB
  const int tid = threadIdx.x;
  const int wave = tid >> 6, lane = tid & 63;
  // rectangle decode: 8 rects = 4(x) x 2(g); rect = 8x x 12g; g = z + 3*y
  const int bid = (int)blockIdx.x;
  const int xcd = bid & 7;
  const int rr = bid >> 3;                  // [0,96)
  const int rgx = xcd % 2, rxx = xcd / 2;   // g-half, x-quarter
  const int gl = rr % 12, xl = rr / 12;     // g fastest
  const int g = rgx * 12 + gl;              // [0,24)
  const int bx = rxx * 8 + xl;              // [0,32)
  const int wz = g % 3;                     // weight: 0=q,1=k,2=v
  const int ky = g / 3;                     // k-split [0,8)
  const int shift = (wz > 0);
  const unsigned short* B = Bq + (size_t)wz * 192 * 12288;
  float* C = (wz == 0) ? qb : (wz == 1 ? kb : vb);
  const int row0 = bx * 128;
  const int ra = (row0 >> 10) + 1;          // z_in view
  const unsigned short* Ab = A + (size_t)(row0 + ra) * 12288;
  const int srow = lane >> 3;
  const int swc = ((lane & 7) ^ srow) * 8;  // pre-swizzled global col
  const int wm = wave & 1, wn = wave >> 1;
  const int lr = lane & 15;
  const int hi = lane >> 4;
  const int l7 = lane & 7;
  const int ksw0 = (hi ^ l7) * 8;
  const int ksw1 = ((4 + hi) ^ l7) * 8;
  const int kbeg = ky * 1536;               // 12288/8
  f32x4 acc[4][6] = {};
  auto stage = [&](int buf, int t) {
    const int k0 = kbeg + t * 64;
    // 40 chunks of 8 rows: 0..15 = A, 16..39 = B; 10 per wave
#pragma unroll
    for (int it = 0; it < 10; ++it) {
      int c = wave * 10 + it;
      if (c < 16) {
        int r = c * 8 + srow;
        load_lds16(Ab + (size_t)r * 12288 + k0 + swc, &sA[buf][c * 512]);
      } else {
        int cb = c - 16;
        int r = cb * 8 + srow;
        load_lds16(B + (size_t)r * 12288 + k0 + swc, &sB[buf][cb * 512]);
      }
    }
  };
  stage(0, 0);
  __syncthreads();
  for (int t = 0; t < 24; ++t) {
    const int cur = t & 1;
    if (t + 1 < 24) stage(cur ^ 1, t + 1);
    const unsigned short* cA = &sA[cur][0];
    const unsigned short* cB = &sB[cur][0];
#pragma unroll
    for (int ks = 0; ks < 2; ++ks) {
      const int ko = ks ? ksw1 : ksw0;
      short8 af[4], bfr[6];
#pragma unroll
      for (int i = 0; i < 4; ++i)
        af[i] = *(const short8*)&cA[(wm * 64 + i * 16 + lr) * 64 + ko];
#pragma unroll
      for (int j = 0; j < 6; ++j)
        bfr[j] = *(const short8*)&cB[(wn * 96 + j * 16 + lr) * 64 + ko];
#pragma unroll
      for (int i = 0; i < 4; ++i)
#pragma unroll
        for (int j = 0; j < 6; ++j)
          acc[i][j] = __builtin_amdgcn_mfma_f32_16x16x32_bf16(af[i], bfr[j], acc[i][j], 0, 0, 0);
    }
    __syncthreads();
  }
  const int rbase = row0 + wm * 64 + (lane >> 4) * 4;
  const int cbase = wn * 96 + lr;
#pragma unroll
  for (int j = 0; j < 6; ++j) {
    int col = cbase + j * 16;
#pragma unroll
    for (int i = 0; i < 4; ++i)
#pragma unroll
      for (int r = 0; r < 4; ++r) {
        int rw = rbase + i * 16 + r;
        if (shift) {
          if ((rw & 1023) == 1023) continue;  // dropped (next batch's row 0 = bias)
          rw += 1;
        }
        atomicAdd(C + (size_t)rw * 192 + col, acc[i][j][r]);
      }
  }
}

// ---------------------------------------------------------------------------
// Attention, two-pass flash-decode.
// ---------------------------------------------------------------------------
__global__ __launch_bounds__(256) void attn_pass1(
    const float* __restrict__ q, const float* __restrict__ k,
    const float* __restrict__ v, float* __restrict__ P) {
  const int wave = threadIdx.x >> 6, lane = threadIdx.x & 63;
  const int task = (int)blockIdx.x * 4 + wave;  // 0..9215
  const int bh = task / 288, t = task % 288;
  const int b = bh >> 3, h = bh & 7;
  int g8 = 0;
  while (4 * (g8 + 1) * (g8 + 2) <= t) ++g8;
  const int r = t - 4 * g8 * (g8 + 1);
  const int qg = g8 * 8 + r / (g8 + 1);
  const int chunk = r % (g8 + 1);
  const int qi = lane & 15, ks = lane >> 4;
  const int qpos = qg * 16 + qi;
  const int n = b * 1024 + qpos;
  const float scale = 0.20412414523193154f;  // 1/sqrt(24)
  float qv[24];
  const float* qr = q + (size_t)n * 192 + h * 24;
#pragma unroll
  for (int d = 0; d < 24; ++d) qv[d] = qr[d] * scale;
  float m = -1e30f, l = 0.0f, ov[24] = {};
  const float* kbp = k + (size_t)b * 1024 * 192 + h * 24;
  const float* vbp = v + (size_t)b * 1024 * 192 + h * 24;
  const int kend = min(qpos, chunk * 128 + 127);
  for (int kp = chunk * 128 + ks; kp <= kend; kp += 4) {
    const f32x4* kr = (const f32x4*)(kbp + (size_t)kp * 192);
    float s0 = 0.0f, s1 = 0.0f, s2 = 0.0f;
#pragma unroll
    for (int j = 0; j < 2; ++j) {
      f32x4 k0 = kr[j * 3 + 0], k1 = kr[j * 3 + 1], k2 = kr[j * 3 + 2];
#pragma unroll
      for (int e = 0; e < 4; ++e) {
        s0 += qv[(j * 3 + 0) * 4 + e] * k0[e];
        s1 += qv[(j * 3 + 1) * 4 + e] * k1[e];
        s2 += qv[(j * 3 + 2) * 4 + e] * k2[e];
      }
    }
    float s = s0 + s1 + s2;
    float mn = fmaxf(m, s);
    float corr = __expf(m - mn);
    float p = __expf(s - mn);
    const f32x4* vr = (const f32x4*)(vbp + (size_t)kp * 192);
    l = l * corr + p;
#pragma unroll
    for (int j = 0; j < 6; ++j) {
      f32x4 vvv = vr[j];
#pragma unroll
      for (int e = 0; e < 4; ++e) ov[j * 4 + e] = ov[j * 4 + e] * corr + p * vvv[e];
    }
    m = mn;
  }
  // merge the 4 k-slices (lanes qi, qi+16, qi+32, qi+48)
#pragma unroll
  for (int off = 16; off < 64; off <<= 1) {
    float m2 = __shfl_xor(m, off);
    float l2 = __shfl_xor(l, off);
    float mn = fmaxf(m, m2);
    float c1 = __expf(m - mn), c2 = __expf(m2 - mn);
    l = l * c1 + l2 * c2;
#pragma unroll
    for (int d = 0; d < 24; ++d) {
      float o2 = __shfl_xor(ov[d], off);
      ov[d] = ov[d] * c1 + o2 * c2;
    }
    m = mn;
  }
  if (ks == 0) {
    float* pr = P + ((size_t)task * 16 + qi) * 28;
    pr[0] = m;
    pr[1] = l;
#pragma unroll
    for (int d = 0; d < 24; ++d) pr[2 + d] = ov[d];
  }
}

__global__ __launch_bounds__(192) void attn_merge(
    const float* __restrict__ P, unsigned short* __restrict__ o) {
  const int n = blockIdx.x;            // 0..4095
  const int tid = threadIdx.x;
  const int h = tid / 24, d = tid - h * 24;
  const int b = n >> 10, qpos = n & 1023;
  const int qg = qpos >> 4, qi = qpos & 15;
  const int g8 = qg >> 3;
  const int nch = g8 + 1;              // == qpos/128 + 1 for all qi in group
  const int bh = b * 8 + h;
  const int base = bh * 288 + 4 * g8 * (g8 + 1) + (qg - g8 * 8) * (g8 + 1);
  float M = -1e30f;
  for (int c = 0; c < nch; ++c)
    M = fmaxf(M, P[((size_t)(base + c) * 16 + qi) * 28]);
  float L = 0.0f, OV = 0.0f;
  for (int c = 0; c < nch; ++c) {
    const float* pr = P + ((size_t)(base + c) * 16 + qi) * 28;
    float w = __expf(pr[0] - M);
    L += pr[1] * w;
    OV += pr[2 + d] * w;
  }
  o[(size_t)n * 192 + h * 24 + d] = f2b(OV / L);
}

// per-row: p = dot(Dz,x)/(||Dz||+eps)^2 ; x -= p*Dz ; xb = bf16(x)
__global__ __launch_bounds__(256) void proj_update(
    const float* __restrict__ Dz, float* __restrict__ x,
    unsigned short* __restrict__ xb) {
  const int n = blockIdx.x;
  const int tid = threadIdx.x;
  const float* dz = Dz + (size_t)n * 768;
  float* xr = x + (size_t)n * 768;
  float dot = 0.0f, s2 = 0.0f;
  for (int i = tid; i < 768; i += 256) {
    float a = dz[i], c = xr[i];
    dot += a * c;
    s2 += a * a;
  }
#pragma unroll
  for (int o2 = 32; o2; o2 >>= 1) {
    dot += __shfl_down(dot, o2);
    s2 += __shfl_down(s2, o2);
  }
  __shared__ float sd[4], ss[4], sp;
  const int wave = tid >> 6, lane = tid & 63;
  if (lane == 0) { sd[wave] = dot; ss[wave] = s2; }
  __syncthreads();
  if (tid == 0) {
    float Dd = sd[0] + sd[1] + sd[2] + sd[3];
    float S = ss[0] + ss[1] + ss[2] + ss[3];
    float nrm = sqrtf(S) + 1e-6f;
    sp = Dd / (nrm * nrm);
  }
  __syncthreads();
  float p = sp;
  for (int i = tid; i < 768; i += 256) {
    float nx = xr[i] - p * dz[i];
    xr[i] = nx;
    xb[(size_t)n * 768 + i] = f2b(nx);
  }
}

DEVFN int sanitize(int v) { return (v & 0x8000) ? 0 : v; }  // -0/neg codes -> 0

// top-32 of z_novel row (bf16 codes nonneg => int order = value order);
// emits 32 (idx,val) pairs per row (slot order arbitrary).
__global__ __launch_bounds__(256) void topk_rows(
    const unsigned short* __restrict__ zbuf, int* __restrict__ idxo,
    float* __restrict__ valo) {
  const int n = blockIdx.x;
  const int b = n >> 10;
  const int tid = threadIdx.x;
  const int wave = tid >> 6, lane = tid & 63;
  const uint4v* zr = (const uint4v*)(zbuf + (size_t)(n + b + 1) * 12288);
  uint4v pk[6];
#pragma unroll
  for (int j = 0; j < 6; ++j) pk[j] = zr[tid * 6 + j];
  __shared__ int swsum[4];
  __shared__ int seq[256];
  __shared__ int spcnt;
  int lo = 0, hi = 0x7F7F;
  while (lo < hi) {
    int mid = (lo + hi) >> 1;
    int c = 0;
#pragma unroll
    for (int j = 0; j < 6; ++j)
#pragma unroll
      for (int e = 0; e < 4; ++e) {
        unsigned int u = pk[j][e];
        c += (sanitize((int)(u & 0xffffu)) > mid) + (sanitize((int)(u >> 16)) > mid);
      }
#pragma unroll
    for (int o2 = 32; o2; o2 >>= 1) c += __shfl_down(c, o2);
    if (lane == 0) swsum[wave] = c;
    __syncthreads();
    int total = swsum[0] + swsum[1] + swsum[2] + swsum[3];
    __syncthreads();
    if (total < 32) hi = mid; else lo = mid + 1;
  }
  const int T = lo;
  int cgt = 0, ceq = 0;
#pragma unroll
  for (int j = 0; j < 6; ++j)
#pragma unroll
    for (int e = 0; e < 4; ++e) {
      unsigned int u = pk[j][e];
      int v0 = sanitize((int)(u & 0xffffu)), v1 = sanitize((int)(u >> 16));
      cgt += (v0 > T) + (v1 > T);
      ceq += (v0 == T) + (v1 == T);
    }
  int cg = cgt;
#pragma unroll
  for (int o2 = 32; o2; o2 >>= 1) cg += __shfl_down(cg, o2);
  if (lane == 0) swsum[wave] = cg;
  seq[tid] = ceq;
  if (tid == 0) spcnt = 0;
  __syncthreads();
  const int total_gt = swsum[0] + swsum[1] + swsum[2] + swsum[3];
  for (int o2 = 1; o2 < 256; o2 <<= 1) {
    int vv = (tid >= o2) ? seq[tid - o2] : 0;
    __syncthreads();
    seq[tid] += vv;
    __syncthreads();
  }
  const int quota = 32 - total_gt;
  int rank = seq[tid] - ceq;
  int* irow = idxo + (size_t)n * 32;
  float* vrow = valo + (size_t)n * 32;
#pragma unroll
  for (int j = 0; j < 6; ++j)
#pragma unroll
    for (int e = 0; e < 4; ++e) {
      unsigned int u = pk[j][e];
#pragma unroll
      for (int hf = 0; hf < 2; ++hf) {
        int v = sanitize(hf ? (int)(u >> 16) : (int)(u & 0xffffu));
        bool kp = false;
        if (v > T) kp = true;
        else if (v == T) { if (rank < quota) kp = true; ++rank; }
        if (kp) {
          int pos = atomicAdd(&spcnt, 1);
          irow[pos] = tid * 48 + j * 8 + e * 2 + hf;
          vrow[pos] = b2f((unsigned short)v);
        }
      }
    }
}

// out = x_input - x_final + sum_j val_j * D[idx_j,:]   (f32 in, f32 out)
__global__ __launch_bounds__(256) void sparse_recons(
    const int* __restrict__ idxo, const float* __restrict__ valo,
    const float* __restrict__ x, const float* __restrict__ xin,
    const float* __restrict__ D, float* __restrict__ out) {
  const int n = blockIdx.x;
  const int t = threadIdx.x;
  __shared__ int sidx[32];
  __shared__ float sval[32];
  if (t < 32) { sidx[t] = idxo[(size_t)n * 32 + t]; sval[t] = valo[(size_t)n * 32 + t]; }
  __syncthreads();
  float acc[3];
#pragma unroll
  for (int u = 0; u < 3; ++u) {
    size_t i = (size_t)n * 768 + t + u * 256;
    acc[u] = xin[i] - x[i];
  }
  for (int j = 0; j < 32; ++j) {
    size_t base = (size_t)sidx[j] * 768;
    float vj = sval[j];
#pragma unroll
    for (int u = 0; u < 3; ++u) acc[u] += vj * D[base + t + u * 256];
  }
#pragma unroll
  for (int u = 0; u < 3; ++u) out[(size_t)n * 768 + t + u * 256] = acc[u];
}

// ===========================================================================
extern "C" void kernel_launch(void* const* d_in, const int* in_sizes, int n_in,
                              void* d_out, int out_size, void* d_ws, size_t ws_size,
                              hipStream_t stream) {
  (void)in_sizes; (void)n_in;
  const float* xin  = (const float*)d_in[0];
  const float* D    = (const float*)d_in[1];
  const float* bvec = (const float*)d_in[2];
  const float* Wq   = (const float*)d_in[3];
  const float* bq   = (const float*)d_in[4];
  const float* Wk   = (const float*)d_in[5];
  const float* bk   = (const float*)d_in[6];
  const float* Wv   = (const float*)d_in[7];
  const float* bv   = (const float*)d_in[8];
  const float* Wo   = (const float*)d_in[9];
  const float* bo   = (const float*)d_in[10];
  const float LAM = 1.0f / 3072.0f;

  char* ws = (char*)d_ws;
  size_t off = 0;
  auto alloc = [&](size_t bytes) {
    void* p = ws + off;
    off += (bytes + 255) & ~(size_t)255;
    return p;
  };
  unsigned short* zbuf = (unsigned short*)alloc((size_t)4 * 1025 * 12288 * 2);
  unsigned short* zpred_ = zbuf;  // alias: lifetimes disjoint
  float* attnP = (float*)zbuf;    // alias: partials live between qkv and Wo GEMMs
  float* x           = (float*)alloc((size_t)4096 * 768 * 4);
  unsigned short* xb = (unsigned short*)alloc((size_t)4096 * 768 * 2);
  float* qb  = (float*)alloc((size_t)4096 * 192 * 4);
  float* kb  = (float*)alloc((size_t)4096 * 192 * 4);
  float* vb  = (float*)alloc((size_t)4096 * 192 * 4);
  unsigned short* ob = (unsigned short*)alloc((size_t)4096 * 192 * 2);
  float* Dz  = (float*)alloc((size_t)4096 * 768 * 4);
  int* idxo  = (int*)alloc((size_t)4096 * 32 * 4);
  float* valo = (float*)alloc((size_t)4096 * 32 * 4);
  const size_t WQKV = (size_t)192 * 12288;   // per (layer, weight)
  unsigned short* WqkvT = (unsigned short*)alloc((size_t)6 * WQKV * 2);
  unsigned short* WoT   = (unsigned short*)alloc((size_t)2 * 12288 * 192 * 2);
  unsigned short* Dbt   = (unsigned short*)alloc((size_t)12288 * 768 * 2);
  unsigned short* Dt    = (unsigned short*)alloc((size_t)768 * 12288 * 2);
  const size_t NEED = off;  // ~219.8 MB (confirmed fitting in R5/R6)

  if (ws_size < NEED) {  // safety net (should never fire)
    fill_out_zero<<<(out_size + 255) / 256, 256, 0, stream>>>((float*)d_out, out_size);
    return;
  }

  init_x<<<12288, 256, 0, stream>>>(xin, bvec, x, xb);
  conv_f2b<<<9216, 256, 0, stream>>>(D, Dbt);
  transpose_f2b<<<dim3(384, 24), 256, 0, stream>>>(D, Dt, 12288, 768);
  for (int l = 0; l < 2; ++l) {
    transpose_f2b<<<dim3(384, 6), 256, 0, stream>>>(
        Wq + (size_t)l * 12288 * 192, WqkvT + (size_t)(l * 3 + 0) * WQKV, 12288, 192);
    transpose_f2b<<<dim3(384, 6), 256, 0, stream>>>(
        Wk + (size_t)l * 12288 * 192, WqkvT + (size_t)(l * 3 + 1) * WQKV, 12288, 192);
    transpose_f2b<<<dim3(384, 6), 256, 0, stream>>>(
        Wv + (size_t)l * 12288 * 192, WqkvT + (size_t)(l * 3 + 2) * WQKV, 12288, 192);
    transpose_f2b<<<dim3(6, 384), 256, 0, stream>>>(
        Wo + (size_t)l * 192 * 12288, WoT + (size_t)l * 12288 * 192, 192, 12288);
  }

  for (int l = 0; l < 2; ++l) {
    // z_in = relu(LAM * x @ D^T) -> zbuf shifted rows [b*1025+1 ..]
    // grid 32x96 -> 1-D 3072, XCD-rect 16x x 24y
    gemm_bt2<unsigned short, true, 1, false, false, 32, 96, 1, 16, 24>
        <<<3072, 256, 0, stream>>>(xb, Dbt, zbuf, nullptr, 768, 12288, LAM);
    // q/k/v from the SAME z_in view; k/v stored row-shifted (z_ctx shift).
    // Bias prefill doubles as the zero-context row (in-batch row 0) for k/v.
    fill_bias<<<3072, 256, 0, stream>>>(qb, bq + (size_t)l * 192, 192);
    fill_bias<<<3072, 256, 0, stream>>>(kb, bk + (size_t)l * 192, 192);
    fill_bias<<<3072, 256, 0, stream>>>(vb, bv + (size_t)l * 192, 192);
    // fused q/k/v GEMM, 1-D 768 blocks, XCD-rect 8x x (4y x 3z)
    gemm_qkv<<<768, 256, 0, stream>>>(
        zbuf, WqkvT + (size_t)(l * 3) * WQKV, qb, kb, vb);
    // Attention (z_in in zbuf is dead now; attnP scratch aliases it)
    attn_pass1<<<2304, 256, 0, stream>>>(qb, kb, vb, attnP);
    attn_merge<<<4096, 192, 0, stream>>>(attnP, ob);
    // z_pred_ = relu(o @ Wo + bo) -> zpred_ (aliases zbuf; attnP dead)
    gemm_bt2<unsigned short, true, 0, true, false, 32, 96, 1, 16, 24>
        <<<3072, 256, 0, stream>>>(
        ob, WoT + (size_t)l * 12288 * 192, zpred_, bo + (size_t)l * 12288, 192, 12288, 1.0f);
    // Dz = z_pred_ @ D  (split-K=4, atomic into zero-prefilled f32)
    fill_bias<<<12288, 256, 0, stream>>>(Dz, nullptr, 768);
    gemm_bt2<float, false, 0, false, true, 32, 6, 4, 16, 6>
        <<<768, 256, 0, stream>>>(zpred_, Dt, Dz, nullptr, 12288, 768, 1.0f);
    proj_update<<<4096, 256, 0, stream>>>(Dz, x, xb);
  }
  // z_novel = relu(LAM * x @ D^T) -> zbuf shifted rows
  gemm_bt2<unsigned short, true, 1, false, false, 32, 96, 1, 16, 24>
      <<<3072, 256, 0, stream>>>(xb, Dbt, zbuf, nullptr, 768, 12288, LAM);
  topk_rows<<<4096, 256, 0, stream>>>(zbuf, idxo, valo);
  sparse_recons<<<4096, 256, 0, stream>>>(idxo, valo, x, xin, D, (float*)d_out);
}

// Round 4
// 1416.936 us; speedup vs baseline: 1.2226x; 1.0439x over previous
//
#include <hip/hip_runtime.h>
#include <hip/hip_bf16.h>

typedef __attribute__((ext_vector_type(4))) float f32x4;
typedef __attribute__((ext_vector_type(8))) short short8;
typedef __attribute__((ext_vector_type(8))) unsigned short ushort8;
typedef __attribute__((ext_vector_type(4))) unsigned short ushort4v;
typedef __attribute__((ext_vector_type(4))) unsigned int uint4v;

#define DEVFN __device__ __forceinline__

DEVFN float b2f(unsigned short u) { return __uint_as_float(((unsigned)u) << 16); }
DEVFN unsigned short f2b(float f) {
  __hip_bfloat16 h = __float2bfloat16(f);
  return __builtin_bit_cast(unsigned short, h);
}

DEVFN void load_lds16(const void* g, void* l) {
  __builtin_amdgcn_global_load_lds(
      (const __attribute__((address_space(1))) unsigned int*)g,
      (__attribute__((address_space(3))) unsigned int*)l, 16, 0, 0);
}

// ===========================================================================

__global__ void fill_out_zero(float* o, int n) {
  int i = blockIdx.x * 256 + threadIdx.x;
  if (i < n) o[i] = 0.0f;
}

__global__ __launch_bounds__(256) void init_x(
    const float* __restrict__ xin, const float* __restrict__ bvec,
    float* __restrict__ x, unsigned short* __restrict__ xb) {
  size_t i = (size_t)blockIdx.x * 256 + threadIdx.x;
  int col = (int)(i % 768);
  float v = xin[i] - bvec[col];
  x[i] = v;
  xb[i] = f2b(v);
}

// buf[i] = bias[i % ld] (or 0 if bias null)
__global__ __launch_bounds__(256) void fill_bias(
    float* __restrict__ buf, const float* __restrict__ bias, int ld) {
  size_t i = (size_t)blockIdx.x * 256 + threadIdx.x;
  buf[i] = bias ? bias[(int)(i % ld)] : 0.0f;
}

// f32 -> bf16 straight convert, 4 elems/thread (n must be /1024)
__global__ __launch_bounds__(256) void conv_f2b(
    const float* __restrict__ in, unsigned short* __restrict__ out) {
  size_t i = ((size_t)blockIdx.x * 256 + threadIdx.x) * 4;
  f32x4 v = *(const f32x4*)(in + i);
  ushort4v w;
#pragma unroll
  for (int e = 0; e < 4; ++e) w[e] = f2b(v[e]);
  *(ushort4v*)(out + i) = w;
}

// out[c][r] = bf16(in[r][c]); R,C multiples of 32; grid (R/32, C/32)
__global__ __launch_bounds__(256) void transpose_f2b(
    const float* __restrict__ in, unsigned short* __restrict__ out,
    int R, int C) {
  __shared__ float tile[32][33];
  int r0 = blockIdx.x * 32, c0 = blockIdx.y * 32;
  int tx = threadIdx.x & 31, ty = threadIdx.x >> 5;
#pragma unroll
  for (int i = 0; i < 4; ++i)
    tile[ty + i * 8][tx] = in[(size_t)(r0 + ty + i * 8) * C + c0 + tx];
  __syncthreads();
#pragma unroll
  for (int i = 0; i < 4; ++i)
    out[(size_t)(c0 + ty + i * 8) * R + r0 + tx] = f2b(tile[tx][ty + i * 8]);
}

// ---------------------------------------------------------------------------
// XCD-rectangle decode: 1-D launch of GX * GY * GZ blocks. bid&7 picks an
// XCD-rectangle (assumes round-robin bid%8 -> XCD; if wrong, perf-neutral).
// Rectangle = RX row-blocks x RG group-ids (g = y + GY*z), g varies fastest.
// Row order is STAGGERED per g-rect so split-K atomic targets of the same
// output tile are never RMW'd from multiple XCDs in lockstep.
// ---------------------------------------------------------------------------
template <int GX, int GY, int GZ, int RX, int RG>
DEVFN void rect_decode(int bid, int& x, int& y, int& z) {
  constexpr int NRG = (GY * GZ) / RG;   // rectangles along g
  const int xcd = bid & 7;
  const int rr = bid >> 3;              // [0, RX*RG)
  const int rgx = xcd % NRG, rxx = xcd / NRG;
  const int gl = rr % RG;
  int xl = rr / RG;
  xl = (xl + rgx * (RX / NRG)) % RX;    // stagger rows across g-rects
  const int g = rgx * RG + gl;
  x = rxx * RX + xl;
  y = g % GY;
  z = g / GY;
}

// ---------------------------------------------------------------------------
// gemm_bt2: C[M,N] = epi(alpha * A[M,K] . B[N,K]^T + bias)  both bf16 K-major.
// 128x128 tile, BK=64, double-buffered global_load_lds staging (one barrier
// per K-iter). LDS XOR-swizzle: physical slot p of row r holds global
// col-block p^(r&7); staging pre-swizzles the GLOBAL source col, reads
// swizzle the slot index -> conflict-free ds_read_b128.
// SC=1: C rows shifted per batch (z storage [b][1+1024][W]).
// 1-D grid of GX*GY*GZ blocks, XCD-rectangle scheduled.
// ---------------------------------------------------------------------------
template <typename CT, bool RELU, int SC, bool BIAS, bool SPLITK,
          int GX, int GY, int GZ, int RX, int RG>
__global__ __launch_bounds__(256) void gemm_bt2(
    const unsigned short* __restrict__ A, const unsigned short* __restrict__ B,
    CT* __restrict__ C, const float* __restrict__ bias,
    int K, int ldc, float alpha) {
  __shared__ unsigned short sA[2][128 * 64];
  __shared__ unsigned short sB[2][128 * 64];
  const int tid = threadIdx.x;
  const int wave = tid >> 6, lane = tid & 63;
  int bx, by, bz;
  rect_decode<GX, GY, GZ, RX, RG>((int)blockIdx.x, bx, by, bz);
  const int row0 = bx * 128, col0 = by * 128;
  const unsigned short* Ab = A + (size_t)row0 * K;
  const unsigned short* Bb = B + (size_t)col0 * K;
  const int srow = lane >> 3;
  const int swc = ((lane & 7) ^ srow) * 8;       // pre-swizzled global col
  const int wm = wave & 1, wn = wave >> 1;
  const int lr = lane & 15;
  const int hi = lane >> 4;
  const int l7 = lane & 7;
  const int ksw0 = (hi ^ l7) * 8;                // swizzled LDS slot, ks=0
  const int ksw1 = ((4 + hi) ^ l7) * 8;          // swizzled LDS slot, ks=1
  const int klen = SPLITK ? (K / GZ) : K;
  const int kbeg = SPLITK ? bz * klen : 0;
  const int nt = klen / 64;
  f32x4 acc[4][4] = {};
  auto stage = [&](int buf, int t) {
    const int k0 = kbeg + t * 64;
#pragma unroll
    for (int it = 0; it < 4; ++it) {
      int chunk = wave * 4 + it;
      int r = chunk * 8 + srow;
      load_lds16(Ab + (size_t)r * K + k0 + swc, &sA[buf][chunk * 512]);
      load_lds16(Bb + (size_t)r * K + k0 + swc, &sB[buf][chunk * 512]);
    }
  };
  stage(0, 0);
  __syncthreads();
  for (int t = 0; t < nt; ++t) {
    const int cur = t & 1;
    if (t + 1 < nt) stage(cur ^ 1, t + 1);
    const unsigned short* cA = &sA[cur][0];
    const unsigned short* cB = &sB[cur][0];
#pragma unroll
    for (int ks = 0; ks < 2; ++ks) {
      const int ko = ks ? ksw1 : ksw0;
      short8 af[4], bfr[4];
#pragma unroll
      for (int i = 0; i < 4; ++i)
        af[i] = *(const short8*)&cA[(wm * 64 + i * 16 + lr) * 64 + ko];
#pragma unroll
      for (int i = 0; i < 4; ++i)
        bfr[i] = *(const short8*)&cB[(wn * 64 + i * 16 + lr) * 64 + ko];
#pragma unroll
      for (int i = 0; i < 4; ++i)
#pragma unroll
        for (int j = 0; j < 4; ++j)
          acc[i][j] = __builtin_amdgcn_mfma_f32_16x16x32_bf16(af[i], bfr[j], acc[i][j], 0, 0, 0);
    }
    __syncthreads();
  }
  const int rc = (SC == 0) ? 0 : ((row0 >> 10) + 1);
  const int rbase = row0 + rc + wm * 64 + (lane >> 4) * 4;
  const int cbase = col0 + wn * 64 + lr;
#pragma unroll
  for (int j = 0; j < 4; ++j) {
    int col = cbase + j * 16;
    float bv = BIAS ? bias[col] : 0.0f;
#pragma unroll
    for (int i = 0; i < 4; ++i) {
#pragma unroll
      for (int r = 0; r < 4; ++r) {
        float vv = acc[i][j][r] * alpha;
        size_t off = (size_t)(rbase + i * 16 + r) * ldc + col;
        if constexpr (SPLITK) {
          atomicAdd((float*)C + off, vv);
        } else {
          vv += bv;
          if (RELU) vv = fmaxf(vv, 0.0f);
          if constexpr (sizeof(CT) == 2) ((unsigned short*)C)[off] = f2b(vv);
          else C[off] = vv;
        }
      }
    }
  }
}

// ---------------------------------------------------------------------------
// gemm_qkv: fused q/k/v projection, ATOMIC-FREE. 384 blocks.
// BM=64, BN=192, split-K=2 (k-halves of 6144). combo = (weight, s):
//   s=0 -> streams bias+partial into qb/kb/vb (shifted rows for k/v;
//          in-batch row 0 keeps the bias prefill, in-batch row 1023 dropped)
//   s=1 -> streams partial into P2[w] (same shift; P2 zero-prefilled)
// then qkv_merge adds P2 into the final buffers. Zero atomics.
// Block decode: XCD i owns 48 consecutive combo-major ranks so its B working
// set is <= 2 weight-slices (4.7 MB, ~L2-resident).
// Same dbuf + XOR-swizzle scheme as gemm_bt2.
// ---------------------------------------------------------------------------
__global__ __launch_bounds__(256) void gemm_qkv(
    const unsigned short* __restrict__ A, const unsigned short* __restrict__ Bq,
    const float* __restrict__ bq, const float* __restrict__ bk,
    const float* __restrict__ bv,
    float* __restrict__ qb, float* __restrict__ kb, float* __restrict__ vb,
    float* __restrict__ P2) {
  __shared__ unsigned short sA[2][64 * 64];    // 16 KB
  __shared__ unsigned short sB[2][192 * 64];   // 48 KB
  const int tid = threadIdx.x;
  const int wave = tid >> 6, lane = tid & 63;
  const int bid = (int)blockIdx.x;
  const int xcd = bid & 7;
  const int rr = bid >> 3;                  // [0,48)
  const int grank = xcd * 48 + rr;          // combo-major global rank
  const int combo = grank >> 6;             // [0,6)
  const int row = grank & 63;               // row-block [0,64)
  const int wz = combo >> 1;                // weight: 0=q,1=k,2=v
  const int s = combo & 1;                  // k-half
  const int shift = (wz > 0);
  const unsigned short* B = Bq + (size_t)wz * 192 * 12288;
  const float* bias = (wz == 0) ? bq : (wz == 1 ? bk : bv);
  float* dst = (s == 0) ? ((wz == 0) ? qb : (wz == 1 ? kb : vb))
                        : (P2 + (size_t)wz * 786432);
  const int row0 = row * 64;
  const int ra = (row0 >> 10) + 1;          // z_in view
  const unsigned short* Ab = A + (size_t)(row0 + ra) * 12288;
  const int srow = lane >> 3;
  const int swc = ((lane & 7) ^ srow) * 8;  // pre-swizzled global col
  const int wm = wave & 1, wn = wave >> 1;
  const int lr = lane & 15;
  const int hi = lane >> 4;
  const int l7 = lane & 7;
  const int ksw0 = (hi ^ l7) * 8;
  const int ksw1 = ((4 + hi) ^ l7) * 8;
  const int kbeg = s * 6144;
  f32x4 acc[2][6] = {};
  auto stage = [&](int buf, int t) {
    const int k0 = kbeg + t * 64;
    // 32 chunks of 8 rows: 0..7 = A (64 rows), 8..31 = B (192 rows); 8/wave
#pragma unroll
    for (int it = 0; it < 8; ++it) {
      int c = wave * 8 + it;
      if (c < 8) {
        int r = c * 8 + srow;
        load_lds16(Ab + (size_t)r * 12288 + k0 + swc, &sA[buf][c * 512]);
      } else {
        int cb = c - 8;
        int r = cb * 8 + srow;
        load_lds16(B + (size_t)r * 12288 + k0 + swc, &sB[buf][cb * 512]);
      }
    }
  };
  stage(0, 0);
  __syncthreads();
  for (int t = 0; t < 96; ++t) {
    const int cur = t & 1;
    if (t + 1 < 96) stage(cur ^ 1, t + 1);
    const unsigned short* cA = &sA[cur][0];
    const unsigned short* cB = &sB[cur][0];
#pragma unroll
    for (int ks = 0; ks < 2; ++ks) {
      const int ko = ks ? ksw1 : ksw0;
      short8 af[2], bfr[6];
#pragma unroll
      for (int i = 0; i < 2; ++i)
        af[i] = *(const short8*)&cA[(wm * 32 + i * 16 + lr) * 64 + ko];
#pragma unroll
      for (int j = 0; j < 6; ++j)
        bfr[j] = *(const short8*)&cB[(wn * 96 + j * 16 + lr) * 64 + ko];
#pragma unroll
      for (int i = 0; i < 2; ++i)
#pragma unroll
        for (int j = 0; j < 6; ++j)
          acc[i][j] = __builtin_amdgcn_mfma_f32_16x16x32_bf16(af[i], bfr[j], acc[i][j], 0, 0, 0);
    }
    __syncthreads();
  }
  const int rbase = row0 + wm * 32 + (lane >> 4) * 4;
  const int cbase = wn * 96 + lr;
#pragma unroll
  for (int j = 0; j < 6; ++j) {
    int col = cbase + j * 16;
    float bvv = (s == 0) ? bias[col] : 0.0f;
#pragma unroll
    for (int i = 0; i < 2; ++i)
#pragma unroll
      for (int r = 0; r < 4; ++r) {
        int rw = rbase + i * 16 + r;
        if (shift) {
          if ((rw & 1023) == 1023) continue;  // dropped (next batch row 0 = bias)
          rw += 1;
        }
        dst[(size_t)rw * 192 + col] = acc[i][j][r] + bvv;
      }
  }
}

// dst[w] += P2[w] elementwise over 3 x 4096 x 192 floats
__global__ __launch_bounds__(256) void qkv_merge(
    const float* __restrict__ P2, float* __restrict__ qb,
    float* __restrict__ kb, float* __restrict__ vb) {
  size_t i = ((size_t)blockIdx.x * 256 + threadIdx.x) * 4;
  const int plane = (int)(i / 786432);
  const size_t o = i - (size_t)plane * 786432;
  float* dst = plane == 0 ? qb : (plane == 1 ? kb : vb);
  f32x4 a = *(const f32x4*)(P2 + i);
  f32x4 b = *(const f32x4*)(dst + o);
#pragma unroll
  for (int e = 0; e < 4; ++e) b[e] += a[e];
  *(f32x4*)(dst + o) = b;
}

// ---------------------------------------------------------------------------
// Attention, two-pass flash-decode.
// ---------------------------------------------------------------------------
__global__ __launch_bounds__(256) void attn_pass1(
    const float* __restrict__ q, const float* __restrict__ k,
    const float* __restrict__ v, float* __restrict__ P) {
  const int wave = threadIdx.x >> 6, lane = threadIdx.x & 63;
  const int task = (int)blockIdx.x * 4 + wave;  // 0..9215
  const int bh = task / 288, t = task % 288;
  const int b = bh >> 3, h = bh & 7;
  int g8 = 0;
  while (4 * (g8 + 1) * (g8 + 2) <= t) ++g8;
  const int r = t - 4 * g8 * (g8 + 1);
  const int qg = g8 * 8 + r / (g8 + 1);
  const int chunk = r % (g8 + 1);
  const int qi = lane & 15, ks = lane >> 4;
  const int qpos = qg * 16 + qi;
  const int n = b * 1024 + qpos;
  const float scale = 0.20412414523193154f;  // 1/sqrt(24)
  float qv[24];
  const float* qr = q + (size_t)n * 192 + h * 24;
#pragma unroll
  for (int d = 0; d < 24; ++d) qv[d] = qr[d] * scale;
  float m = -1e30f, l = 0.0f, ov[24] = {};
  const float* kbp = k + (size_t)b * 1024 * 192 + h * 24;
  const float* vbp = v + (size_t)b * 1024 * 192 + h * 24;
  const int kend = min(qpos, chunk * 128 + 127);
  for (int kp = chunk * 128 + ks; kp <= kend; kp += 4) {
    const f32x4* kr = (const f32x4*)(kbp + (size_t)kp * 192);
    float s0 = 0.0f, s1 = 0.0f, s2 = 0.0f;
#pragma unroll
    for (int j = 0; j < 2; ++j) {
      f32x4 k0 = kr[j * 3 + 0], k1 = kr[j * 3 + 1], k2 = kr[j * 3 + 2];
#pragma unroll
      for (int e = 0; e < 4; ++e) {
        s0 += qv[(j * 3 + 0) * 4 + e] * k0[e];
        s1 += qv[(j * 3 + 1) * 4 + e] * k1[e];
        s2 += qv[(j * 3 + 2) * 4 + e] * k2[e];
      }
    }
    float s = s0 + s1 + s2;
    float mn = fmaxf(m, s);
    float corr = __expf(m - mn);
    float p = __expf(s - mn);
    const f32x4* vr = (const f32x4*)(vbp + (size_t)kp * 192);
    l = l * corr + p;
#pragma unroll
    for (int j = 0; j < 6; ++j) {
      f32x4 vvv = vr[j];
#pragma unroll
      for (int e = 0; e < 4; ++e) ov[j * 4 + e] = ov[j * 4 + e] * corr + p * vvv[e];
    }
    m = mn;
  }
  // merge the 4 k-slices (lanes qi, qi+16, qi+32, qi+48)
#pragma unroll
  for (int off = 16; off < 64; off <<= 1) {
    float m2 = __shfl_xor(m, off);
    float l2 = __shfl_xor(l, off);
    float mn = fmaxf(m, m2);
    float c1 = __expf(m - mn), c2 = __expf(m2 - mn);
    l = l * c1 + l2 * c2;
#pragma unroll
    for (int d = 0; d < 24; ++d) {
      float o2 = __shfl_xor(ov[d], off);
      ov[d] = ov[d] * c1 + o2 * c2;
    }
    m = mn;
  }
  if (ks == 0) {
    float* pr = P + ((size_t)task * 16 + qi) * 28;
    pr[0] = m;
    pr[1] = l;
#pragma unroll
    for (int d = 0; d < 24; ++d) pr[2 + d] = ov[d];
  }
}

__global__ __launch_bounds__(192) void attn_merge(
    const float* __restrict__ P, unsigned short* __restrict__ o) {
  const int n = blockIdx.x;            // 0..4095
  const int tid = threadIdx.x;
  const int h = tid / 24, d = tid - h * 24;
  const int b = n >> 10, qpos = n & 1023;
  const int qg = qpos >> 4, qi = qpos & 15;
  const int g8 = qg >> 3;
  const int nch = g8 + 1;              // == qpos/128 + 1 for all qi in group
  const int bh = b * 8 + h;
  const int base = bh * 288 + 4 * g8 * (g8 + 1) + (qg - g8 * 8) * (g8 + 1);
  float M = -1e30f;
  for (int c = 0; c < nch; ++c)
    M = fmaxf(M, P[((size_t)(base + c) * 16 + qi) * 28]);
  float L = 0.0f, OV = 0.0f;
  for (int c = 0; c < nch; ++c) {
    const float* pr = P + ((size_t)(base + c) * 16 + qi) * 28;
    float w = __expf(pr[0] - M);
    L += pr[1] * w;
    OV += pr[2 + d] * w;
  }
  o[(size_t)n * 192 + h * 24 + d] = f2b(OV / L);
}

// per-row: p = dot(Dz,x)/(||Dz||+eps)^2 ; x -= p*Dz ; xb = bf16(x)
__global__ __launch_bounds__(256) void proj_update(
    const float* __restrict__ Dz, float* __restrict__ x,
    unsigned short* __restrict__ xb) {
  const int n = blockIdx.x;
  const int tid = threadIdx.x;
  const float* dz = Dz + (size_t)n * 768;
  float* xr = x + (size_t)n * 768;
  float dot = 0.0f, s2 = 0.0f;
  for (int i = tid; i < 768; i += 256) {
    float a = dz[i], c = xr[i];
    dot += a * c;
    s2 += a * a;
  }
#pragma unroll
  for (int o2 = 32; o2; o2 >>= 1) {
    dot += __shfl_down(dot, o2);
    s2 += __shfl_down(s2, o2);
  }
  __shared__ float sd[4], ss[4], sp;
  const int wave = tid >> 6, lane = tid & 63;
  if (lane == 0) { sd[wave] = dot; ss[wave] = s2; }
  __syncthreads();
  if (tid == 0) {
    float Dd = sd[0] + sd[1] + sd[2] + sd[3];
    float S = ss[0] + ss[1] + ss[2] + ss[3];
    float nrm = sqrtf(S) + 1e-6f;
    sp = Dd / (nrm * nrm);
  }
  __syncthreads();
  float p = sp;
  for (int i = tid; i < 768; i += 256) {
    float nx = xr[i] - p * dz[i];
    xr[i] = nx;
    xb[(size_t)n * 768 + i] = f2b(nx);
  }
}

DEVFN int sanitize(int v) { return (v & 0x8000) ? 0 : v; }  // -0/neg codes -> 0

// top-32 of z_novel row (bf16 codes nonneg => int order = value order);
// emits 32 (idx,val) pairs per row (slot order arbitrary).
__global__ __launch_bounds__(256) void topk_rows(
    const unsigned short* __restrict__ zbuf, int* __restrict__ idxo,
    float* __restrict__ valo) {
  const int n = blockIdx.x;
  const int b = n >> 10;
  const int tid = threadIdx.x;
  const int wave = tid >> 6, lane = tid & 63;
  const uint4v* zr = (const uint4v*)(zbuf + (size_t)(n + b + 1) * 12288);
  uint4v pk[6];
#pragma unroll
  for (int j = 0; j < 6; ++j) pk[j] = zr[tid * 6 + j];
  __shared__ int swsum[4];
  __shared__ int seq[256];
  __shared__ int spcnt;
  int lo = 0, hi = 0x7F7F;
  while (lo < hi) {
    int mid = (lo + hi) >> 1;
    int c = 0;
#pragma unroll
    for (int j = 0; j < 6; ++j)
#pragma unroll
      for (int e = 0; e < 4; ++e) {
        unsigned int u = pk[j][e];
        c += (sanitize((int)(u & 0xffffu)) > mid) + (sanitize((int)(u >> 16)) > mid);
      }
#pragma unroll
    for (int o2 = 32; o2; o2 >>= 1) c += __shfl_down(c, o2);
    if (lane == 0) swsum[wave] = c;
    __syncthreads();
    int total = swsum[0] + swsum[1] + swsum[2] + swsum[3];
    __syncthreads();
    if (total < 32) hi = mid; else lo = mid + 1;
  }
  const int T = lo;
  int cgt = 0, ceq = 0;
#pragma unroll
  for (int j = 0; j < 6; ++j)
#pragma unroll
    for (int e = 0; e < 4; ++e) {
      unsigned int u = pk[j][e];
      int v0 = sanitize((int)(u & 0xffffu)), v1 = sanitize((int)(u >> 16));
      cgt += (v0 > T) + (v1 > T);
      ceq += (v0 == T) + (v1 == T);
    }
  int cg = cgt;
#pragma unroll
  for (int o2 = 32; o2; o2 >>= 1) cg += __shfl_down(cg, o2);
  if (lane == 0) swsum[wave] = cg;
  seq[tid] = ceq;
  if (tid == 0) spcnt = 0;
  __syncthreads();
  const int total_gt = swsum[0] + swsum[1] + swsum[2] + swsum[3];
  for (int o2 = 1; o2 < 256; o2 <<= 1) {
    int vv = (tid >= o2) ? seq[tid - o2] : 0;
    __syncthreads();
    seq[tid] += vv;
    __syncthreads();
  }
  const int quota = 32 - total_gt;
  int rank = seq[tid] - ceq;
  int* irow = idxo + (size_t)n * 32;
  float* vrow = valo + (size_t)n * 32;
#pragma unroll
  for (int j = 0; j < 6; ++j)
#pragma unroll
    for (int e = 0; e < 4; ++e) {
      unsigned int u = pk[j][e];
#pragma unroll
      for (int hf = 0; hf < 2; ++hf) {
        int v = sanitize(hf ? (int)(u >> 16) : (int)(u & 0xffffu));
        bool kp = false;
        if (v > T) kp = true;
        else if (v == T) { if (rank < quota) kp = true; ++rank; }
        if (kp) {
          int pos = atomicAdd(&spcnt, 1);
          irow[pos] = tid * 48 + j * 8 + e * 2 + hf;
          vrow[pos] = b2f((unsigned short)v);
        }
      }
    }
}

// out = x_input - x_final + sum_j val_j * D[idx_j,:]   (f32 in, f32 out)
__global__ __launch_bounds__(256) void sparse_recons(
    const int* __restrict__ idxo, const float* __restrict__ valo,
    const float* __restrict__ x, const float* __restrict__ xin,
    const float* __restrict__ D, float* __restrict__ out) {
  const int n = blockIdx.x;
  const int t = threadIdx.x;
  __shared__ int sidx[32];
  __shared__ float sval[32];
  if (t < 32) { sidx[t] = idxo[(size_t)n * 32 + t]; sval[t] = valo[(size_t)n * 32 + t]; }
  __syncthreads();
  float acc[3];
#pragma unroll
  for (int u = 0; u < 3; ++u) {
    size_t i = (size_t)n * 768 + t + u * 256;
    acc[u] = xin[i] - x[i];
  }
  for (int j = 0; j < 32; ++j) {
    size_t base = (size_t)sidx[j] * 768;
    float vj = sval[j];
#pragma unroll
    for (int u = 0; u < 3; ++u) acc[u] += vj * D[base + t + u * 256];
  }
#pragma unroll
  for (int u = 0; u < 3; ++u) out[(size_t)n * 768 + t + u * 256] = acc[u];
}

// ===========================================================================
extern "C" void kernel_launch(void* const* d_in, const int* in_sizes, int n_in,
                              void* d_out, int out_size, void* d_ws, size_t ws_size,
                              hipStream_t stream) {
  (void)in_sizes; (void)n_in;
  const float* xin  = (const float*)d_in[0];
  const float* D    = (const float*)d_in[1];
  const float* bvec = (const float*)d_in[2];
  const float* Wq   = (const float*)d_in[3];
  const float* bq   = (const float*)d_in[4];
  const float* Wk   = (const float*)d_in[5];
  const float* bk   = (const float*)d_in[6];
  const float* Wv   = (const float*)d_in[7];
  const float* bv   = (const float*)d_in[8];
  const float* Wo   = (const float*)d_in[9];
  const float* bo   = (const float*)d_in[10];
  const float LAM = 1.0f / 3072.0f;

  char* ws = (char*)d_ws;
  size_t off = 0;
  auto alloc = [&](size_t bytes) {
    void* p = ws + off;
    off += (bytes + 255) & ~(size_t)255;
    return p;
  };
  unsigned short* zbuf = (unsigned short*)alloc((size_t)4 * 1025 * 12288 * 2);
  unsigned short* zpred_ = zbuf;  // alias: lifetimes disjoint
  float* attnP = (float*)zbuf;    // alias: partials live between qkv and Wo GEMMs
  float* x           = (float*)alloc((size_t)4096 * 768 * 4);
  unsigned short* xb = (unsigned short*)alloc((size_t)4096 * 768 * 2);
  float* qb  = (float*)alloc((size_t)4096 * 192 * 4);
  float* kb  = (float*)alloc((size_t)4096 * 192 * 4);
  float* vb  = (float*)alloc((size_t)4096 * 192 * 4);
  unsigned short* ob = (unsigned short*)alloc((size_t)4096 * 192 * 2);
  float* Dz  = (float*)alloc((size_t)4096 * 768 * 4);
  int* idxo  = (int*)alloc((size_t)4096 * 32 * 4);
  float* valo = (float*)alloc((size_t)4096 * 32 * 4);
  const size_t WQKV = (size_t)192 * 12288;   // per (layer, weight)
  unsigned short* WqkvT = (unsigned short*)alloc((size_t)6 * WQKV * 2);
  unsigned short* WoT   = (unsigned short*)alloc((size_t)2 * 12288 * 192 * 2);
  unsigned short* Dbt   = (unsigned short*)alloc((size_t)12288 * 768 * 2);
  unsigned short* Dt    = (unsigned short*)alloc((size_t)768 * 12288 * 2);
  const size_t NEED = off;  // ~219.8 MB (confirmed fitting in R5/R6)
  // qkv split-1 partials alias the (dead at qkv time) Dz buffer: 9.44 MB <= 12.6 MB
  float* P2 = Dz;

  if (ws_size < NEED) {  // safety net (should never fire)
    fill_out_zero<<<(out_size + 255) / 256, 256, 0, stream>>>((float*)d_out, out_size);
    return;
  }

  init_x<<<12288, 256, 0, stream>>>(xin, bvec, x, xb);
  conv_f2b<<<9216, 256, 0, stream>>>(D, Dbt);
  transpose_f2b<<<dim3(384, 24), 256, 0, stream>>>(D, Dt, 12288, 768);
  for (int l = 0; l < 2; ++l) {
    transpose_f2b<<<dim3(384, 6), 256, 0, stream>>>(
        Wq + (size_t)l * 12288 * 192, WqkvT + (size_t)(l * 3 + 0) * WQKV, 12288, 192);
    transpose_f2b<<<dim3(384, 6), 256, 0, stream>>>(
        Wk + (size_t)l * 12288 * 192, WqkvT + (size_t)(l * 3 + 1) * WQKV, 12288, 192);
    transpose_f2b<<<dim3(384, 6), 256, 0, stream>>>(
        Wv + (size_t)l * 12288 * 192, WqkvT + (size_t)(l * 3 + 2) * WQKV, 12288, 192);
    transpose_f2b<<<dim3(6, 384), 256, 0, stream>>>(
        Wo + (size_t)l * 192 * 12288, WoT + (size_t)l * 12288 * 192, 192, 12288);
  }

  for (int l = 0; l < 2; ++l) {
    // z_in = relu(LAM * x @ D^T) -> zbuf shifted rows [b*1025+1 ..]
    gemm_bt2<unsigned short, true, 1, false, false, 32, 96, 1, 16, 24>
        <<<3072, 256, 0, stream>>>(xb, Dbt, zbuf, nullptr, 768, 12288, LAM);
    // k/v row-0 prefill (= zero-context bias row); qb fully written by qkv s=0.
    fill_bias<<<3072, 256, 0, stream>>>(kb, bk + (size_t)l * 192, 192);
    fill_bias<<<3072, 256, 0, stream>>>(vb, bv + (size_t)l * 192, 192);
    // P2 zero-prefill (rows (b,0) of k/v planes must read as 0 in the merge)
    fill_bias<<<9216, 256, 0, stream>>>(P2, nullptr, 192);
    // atomic-free fused q/k/v: split 0 -> final bufs, split 1 -> P2; merge.
    gemm_qkv<<<384, 256, 0, stream>>>(
        zbuf, WqkvT + (size_t)(l * 3) * WQKV,
        bq + (size_t)l * 192, bk + (size_t)l * 192, bv + (size_t)l * 192,
        qb, kb, vb, P2);
    qkv_merge<<<2304, 256, 0, stream>>>(P2, qb, kb, vb);
    // Attention (z_in in zbuf is dead now; attnP scratch aliases it)
    attn_pass1<<<2304, 256, 0, stream>>>(qb, kb, vb, attnP);
    attn_merge<<<4096, 192, 0, stream>>>(attnP, ob);
    // z_pred_ = relu(o @ Wo + bo) -> zpred_ (aliases zbuf; attnP dead)
    gemm_bt2<unsigned short, true, 0, true, false, 32, 96, 1, 16, 24>
        <<<3072, 256, 0, stream>>>(
        ob, WoT + (size_t)l * 12288 * 192, zpred_, bo + (size_t)l * 12288, 192, 12288, 1.0f);
    // Dz = z_pred_ @ D  (split-K=4, atomic into zero-prefilled f32; P2 dead)
    fill_bias<<<12288, 256, 0, stream>>>(Dz, nullptr, 768);
    gemm_bt2<float, false, 0, false, true, 32, 6, 4, 16, 6>
        <<<768, 256, 0, stream>>>(zpred_, Dt, Dz, nullptr, 12288, 768, 1.0f);
    proj_update<<<4096, 256, 0, stream>>>(Dz, x, xb);
  }
  // z_novel = relu(LAM * x @ D^T) -> zbuf shifted rows
  gemm_bt2<unsigned short, true, 1, false, false, 32, 96, 1, 16, 24>
      <<<3072, 256, 0, stream>>>(xb, Dbt, zbuf, nullptr, 768, 12288, LAM);
  topk_rows<<<4096, 256, 0, stream>>>(zbuf, idxo, valo);
  sparse_recons<<<4096, 256, 0, stream>>>(idxo, valo, x, xin, D, (float*)d_out);
}

// Round 5
// 1405.051 us; speedup vs baseline: 1.2329x; 1.0085x over previous
//
#include <hip/hip_runtime.h>
#include <hip/hip_bf16.h>

typedef __attribute__((ext_vector_type(4))) float f32x4;
typedef __attribute__((ext_vector_type(8))) short short8;
typedef __attribute__((ext_vector_type(8))) unsigned short ushort8;
typedef __attribute__((ext_vector_type(4))) unsigned short ushort4v;
typedef __attribute__((ext_vector_type(4))) unsigned int uint4v;

#define DEVFN __device__ __forceinline__

DEVFN float b2f(unsigned short u) { return __uint_as_float(((unsigned)u) << 16); }
DEVFN unsigned short f2b(float f) {
  __hip_bfloat16 h = __float2bfloat16(f);
  return __builtin_bit_cast(unsigned short, h);
}

DEVFN void load_lds16(const void* g, void* l) {
  __builtin_amdgcn_global_load_lds(
      (const __attribute__((address_space(1))) unsigned int*)g,
      (__attribute__((address_space(3))) unsigned int*)l, 16, 0, 0);
}

// ===========================================================================

__global__ void fill_out_zero(float* o, int n) {
  int i = blockIdx.x * 256 + threadIdx.x;
  if (i < n) o[i] = 0.0f;
}

__global__ __launch_bounds__(256) void init_x(
    const float* __restrict__ xin, const float* __restrict__ bvec,
    float* __restrict__ x, unsigned short* __restrict__ xb) {
  size_t i = (size_t)blockIdx.x * 256 + threadIdx.x;
  int col = (int)(i % 768);
  float v = xin[i] - bvec[col];
  x[i] = v;
  xb[i] = f2b(v);
}

// buf[i] = bias[i % ld] (or 0 if bias null)
__global__ __launch_bounds__(256) void fill_bias(
    float* __restrict__ buf, const float* __restrict__ bias, int ld) {
  size_t i = (size_t)blockIdx.x * 256 + threadIdx.x;
  buf[i] = bias ? bias[(int)(i % ld)] : 0.0f;
}

// f32 -> bf16 straight convert, 4 elems/thread (n must be /1024)
__global__ __launch_bounds__(256) void conv_f2b(
    const float* __restrict__ in, unsigned short* __restrict__ out) {
  size_t i = ((size_t)blockIdx.x * 256 + threadIdx.x) * 4;
  f32x4 v = *(const f32x4*)(in + i);
  ushort4v w;
#pragma unroll
  for (int e = 0; e < 4; ++e) w[e] = f2b(v[e]);
  *(ushort4v*)(out + i) = w;
}

// out[c][r] = bf16(in[r][c]); R,C multiples of 32; grid (R/32, C/32)
__global__ __launch_bounds__(256) void transpose_f2b(
    const float* __restrict__ in, unsigned short* __restrict__ out,
    int R, int C) {
  __shared__ float tile[32][33];
  int r0 = blockIdx.x * 32, c0 = blockIdx.y * 32;
  int tx = threadIdx.x & 31, ty = threadIdx.x >> 5;
#pragma unroll
  for (int i = 0; i < 4; ++i)
    tile[ty + i * 8][tx] = in[(size_t)(r0 + ty + i * 8) * C + c0 + tx];
  __syncthreads();
#pragma unroll
  for (int i = 0; i < 4; ++i)
    out[(size_t)(c0 + ty + i * 8) * R + r0 + tx] = f2b(tile[tx][ty + i * 8]);
}

// ---------------------------------------------------------------------------
// XCD-rectangle decode: 1-D launch of GX * GY * GZ blocks. bid&7 picks an
// XCD-rectangle (assumes round-robin bid%8 -> XCD; if wrong, perf-neutral).
// Rectangle = RX row-blocks x RG group-ids (g = y + GY*z), g varies fastest.
// Row order is STAGGERED per g-rect so split-K atomic targets of the same
// output tile are never RMW'd from multiple XCDs in lockstep.
// ---------------------------------------------------------------------------
template <int GX, int GY, int GZ, int RX, int RG>
DEVFN void rect_decode(int bid, int& x, int& y, int& z) {
  constexpr int NRG = (GY * GZ) / RG;   // rectangles along g
  const int xcd = bid & 7;
  const int rr = bid >> 3;              // [0, RX*RG)
  const int rgx = xcd % NRG, rxx = xcd / NRG;
  const int gl = rr % RG;
  int xl = rr / RG;
  xl = (xl + rgx * (RX / NRG)) % RX;    // stagger rows across g-rects
  const int g = rgx * RG + gl;
  x = rxx * RX + xl;
  y = g % GY;
  z = g / GY;
}

// ---------------------------------------------------------------------------
// gemm_bt2: C[M,N] = epi(alpha * A[M,K] . B[N,K]^T + bias)  both bf16 K-major.
// 256x256 tile, BK=64, 512 threads (8 waves, 2M x 4N, 128x64 out each).
// Double-buffered global_load_lds staging (stage(t+1) issued before
// compute(t); one barrier per K-iter). LDS XOR-swizzle: physical slot p of
// row r holds global col-block p^(r&7); staging pre-swizzles the GLOBAL
// source col (LDS dest stays linear), reads swizzle the slot index ->
// conflict-free ds_read_b128. 128 KB LDS -> 1 block/CU; per-iter MFMA
// (~640 cyc/SIMD) now exceeds the halved staging service time.
// SC=1: C rows shifted per batch (z storage [b][1+1024][W]; 256 | 1024 so
// each block is within one batch). 1-D grid, XCD-rectangle scheduled.
// ---------------------------------------------------------------------------
template <typename CT, bool RELU, int SC, bool BIAS, bool SPLITK,
          int GX, int GY, int GZ, int RX, int RG>
__global__ __launch_bounds__(512, 2) void gemm_bt2(
    const unsigned short* __restrict__ A, const unsigned short* __restrict__ B,
    CT* __restrict__ C, const float* __restrict__ bias,
    int K, int ldc, float alpha) {
  __shared__ unsigned short sA[2][256 * 64];   // 64 KB
  __shared__ unsigned short sB[2][256 * 64];   // 64 KB
  const int tid = threadIdx.x;
  const int wave = tid >> 6, lane = tid & 63;
  int bx, by, bz;
  rect_decode<GX, GY, GZ, RX, RG>((int)blockIdx.x, bx, by, bz);
  const int row0 = bx * 256, col0 = by * 256;
  const unsigned short* Ab = A + (size_t)row0 * K;
  const unsigned short* Bb = B + (size_t)col0 * K;
  const int srow = lane >> 3;
  const int swc = ((lane & 7) ^ srow) * 8;       // pre-swizzled global col
  const int wm = wave & 1, wn = wave >> 1;       // 2 x 4 wave grid
  const int lr = lane & 15;
  const int hi = lane >> 4;
  const int l7 = lane & 7;
  const int ksw0 = (hi ^ l7) * 8;                // swizzled LDS slot, ks=0
  const int ksw1 = ((4 + hi) ^ l7) * 8;          // swizzled LDS slot, ks=1
  const int klen = SPLITK ? (K / GZ) : K;
  const int kbeg = SPLITK ? bz * klen : 0;
  const int nt = klen / 64;
  f32x4 acc[8][4] = {};
  auto stage = [&](int buf, int t) {
    const int k0 = kbeg + t * 64;
    // 64 chunks of 8 rows x 64 cols: 0..31 = A, 32..63 = B; 8 per wave
#pragma unroll
    for (int it = 0; it < 8; ++it) {
      int c = wave * 8 + it;
      if (c < 32) {
        int r = c * 8 + srow;
        load_lds16(Ab + (size_t)r * K + k0 + swc, &sA[buf][c * 512]);
      } else {
        int cb = c - 32;
        int r = cb * 8 + srow;
        load_lds16(Bb + (size_t)r * K + k0 + swc, &sB[buf][cb * 512]);
      }
    }
  };
  stage(0, 0);
  __syncthreads();
  for (int t = 0; t < nt; ++t) {
    const int cur = t & 1;
    if (t + 1 < nt) stage(cur ^ 1, t + 1);
    const unsigned short* cA = &sA[cur][0];
    const unsigned short* cB = &sB[cur][0];
#pragma unroll
    for (int ks = 0; ks < 2; ++ks) {
      const int ko = ks ? ksw1 : ksw0;
      short8 af[8], bfr[4];
#pragma unroll
      for (int i = 0; i < 8; ++i)
        af[i] = *(const short8*)&cA[(wm * 128 + i * 16 + lr) * 64 + ko];
#pragma unroll
      for (int j = 0; j < 4; ++j)
        bfr[j] = *(const short8*)&cB[(wn * 64 + j * 16 + lr) * 64 + ko];
#pragma unroll
      for (int i = 0; i < 8; ++i)
#pragma unroll
        for (int j = 0; j < 4; ++j)
          acc[i][j] = __builtin_amdgcn_mfma_f32_16x16x32_bf16(af[i], bfr[j], acc[i][j], 0, 0, 0);
    }
    __syncthreads();
  }
  const int rc = (SC == 0) ? 0 : ((row0 >> 10) + 1);
  const int rbase = row0 + rc + wm * 128 + (lane >> 4) * 4;
  const int cbase = col0 + wn * 64 + lr;
#pragma unroll
  for (int j = 0; j < 4; ++j) {
    int col = cbase + j * 16;
    float bv = BIAS ? bias[col] : 0.0f;
#pragma unroll
    for (int i = 0; i < 8; ++i) {
#pragma unroll
      for (int r = 0; r < 4; ++r) {
        float vv = acc[i][j][r] * alpha;
        size_t off = (size_t)(rbase + i * 16 + r) * ldc + col;
        if constexpr (SPLITK) {
          atomicAdd((float*)C + off, vv);
        } else {
          vv += bv;
          if (RELU) vv = fmaxf(vv, 0.0f);
          if constexpr (sizeof(CT) == 2) ((unsigned short*)C)[off] = f2b(vv);
          else C[off] = vv;
        }
      }
    }
  }
}

// ---------------------------------------------------------------------------
// gemm_qkv: fused q/k/v projection, ATOMIC-FREE. 384 blocks.
// BM=64, BN=192, split-K=2 (k-halves of 6144). combo = (weight, s):
//   s=0 -> streams bias+partial into qb/kb/vb (shifted rows for k/v;
//          in-batch row 0 keeps the bias prefill, in-batch row 1023 dropped)
//   s=1 -> streams partial into P2[w] (same shift; P2 zero-prefilled)
// then qkv_merge adds P2 into the final buffers. Zero atomics.
// Block decode: XCD i owns 48 consecutive combo-major ranks so its B working
// set is <= 2 weight-slices (4.7 MB, ~L2-resident).
// Same dbuf + XOR-swizzle scheme as gemm_bt2.
// ---------------------------------------------------------------------------
__global__ __launch_bounds__(256) void gemm_qkv(
    const unsigned short* __restrict__ A, const unsigned short* __restrict__ Bq,
    const float* __restrict__ bq, const float* __restrict__ bk,
    const float* __restrict__ bv,
    float* __restrict__ qb, float* __restrict__ kb, float* __restrict__ vb,
    float* __restrict__ P2) {
  __shared__ unsigned short sA[2][64 * 64];    // 16 KB
  __shared__ unsigned short sB[2][192 * 64];   // 48 KB
  const int tid = threadIdx.x;
  const int wave = tid >> 6, lane = tid & 63;
  const int bid = (int)blockIdx.x;
  const int xcd = bid & 7;
  const int rr = bid >> 3;                  // [0,48)
  const int grank = xcd * 48 + rr;          // combo-major global rank
  const int combo = grank >> 6;             // [0,6)
  const int row = grank & 63;               // row-block [0,64)
  const int wz = combo >> 1;                // weight: 0=q,1=k,2=v
  const int s = combo & 1;                  // k-half
  const int shift = (wz > 0);
  const unsigned short* B = Bq + (size_t)wz * 192 * 12288;
  const float* bias = (wz == 0) ? bq : (wz == 1 ? bk : bv);
  float* dst = (s == 0) ? ((wz == 0) ? qb : (wz == 1 ? kb : vb))
                        : (P2 + (size_t)wz * 786432);
  const int row0 = row * 64;
  const int ra = (row0 >> 10) + 1;          // z_in view
  const unsigned short* Ab = A + (size_t)(row0 + ra) * 12288;
  const int srow = lane >> 3;
  const int swc = ((lane & 7) ^ srow) * 8;  // pre-swizzled global col
  const int wm = wave & 1, wn = wave >> 1;
  const int lr = lane & 15;
  const int hi = lane >> 4;
  const int l7 = lane & 7;
  const int ksw0 = (hi ^ l7) * 8;
  const int ksw1 = ((4 + hi) ^ l7) * 8;
  const int kbeg = s * 6144;
  f32x4 acc[2][6] = {};
  auto stage = [&](int buf, int t) {
    const int k0 = kbeg + t * 64;
    // 32 chunks of 8 rows: 0..7 = A (64 rows), 8..31 = B (192 rows); 8/wave
#pragma unroll
    for (int it = 0; it < 8; ++it) {
      int c = wave * 8 + it;
      if (c < 8) {
        int r = c * 8 + srow;
        load_lds16(Ab + (size_t)r * 12288 + k0 + swc, &sA[buf][c * 512]);
      } else {
        int cb = c - 8;
        int r = cb * 8 + srow;
        load_lds16(B + (size_t)r * 12288 + k0 + swc, &sB[buf][cb * 512]);
      }
    }
  };
  stage(0, 0);
  __syncthreads();
  for (int t = 0; t < 96; ++t) {
    const int cur = t & 1;
    if (t + 1 < 96) stage(cur ^ 1, t + 1);
    const unsigned short* cA = &sA[cur][0];
    const unsigned short* cB = &sB[cur][0];
#pragma unroll
    for (int ks = 0; ks < 2; ++ks) {
      const int ko = ks ? ksw1 : ksw0;
      short8 af[2], bfr[6];
#pragma unroll
      for (int i = 0; i < 2; ++i)
        af[i] = *(const short8*)&cA[(wm * 32 + i * 16 + lr) * 64 + ko];
#pragma unroll
      for (int j = 0; j < 6; ++j)
        bfr[j] = *(const short8*)&cB[(wn * 96 + j * 16 + lr) * 64 + ko];
#pragma unroll
      for (int i = 0; i < 2; ++i)
#pragma unroll
        for (int j = 0; j < 6; ++j)
          acc[i][j] = __builtin_amdgcn_mfma_f32_16x16x32_bf16(af[i], bfr[j], acc[i][j], 0, 0, 0);
    }
    __syncthreads();
  }
  const int rbase = row0 + wm * 32 + (lane >> 4) * 4;
  const int cbase = wn * 96 + lr;
#pragma unroll
  for (int j = 0; j < 6; ++j) {
    int col = cbase + j * 16;
    float bvv = (s == 0) ? bias[col] : 0.0f;
#pragma unroll
    for (int i = 0; i < 2; ++i)
#pragma unroll
      for (int r = 0; r < 4; ++r) {
        int rw = rbase + i * 16 + r;
        if (shift) {
          if ((rw & 1023) == 1023) continue;  // dropped (next batch row 0 = bias)
          rw += 1;
        }
        dst[(size_t)rw * 192 + col] = acc[i][j][r] + bvv;
      }
  }
}

// dst[w] += P2[w] elementwise over 3 x 4096 x 192 floats
__global__ __launch_bounds__(256) void qkv_merge(
    const float* __restrict__ P2, float* __restrict__ qb,
    float* __restrict__ kb, float* __restrict__ vb) {
  size_t i = ((size_t)blockIdx.x * 256 + threadIdx.x) * 4;
  const int plane = (int)(i / 786432);
  const size_t o = i - (size_t)plane * 786432;
  float* dst = plane == 0 ? qb : (plane == 1 ? kb : vb);
  f32x4 a = *(const f32x4*)(P2 + i);
  f32x4 b = *(const f32x4*)(dst + o);
#pragma unroll
  for (int e = 0; e < 4; ++e) b[e] += a[e];
  *(f32x4*)(dst + o) = b;
}

// ---------------------------------------------------------------------------
// Attention, two-pass flash-decode.
// ---------------------------------------------------------------------------
__global__ __launch_bounds__(256) void attn_pass1(
    const float* __restrict__ q, const float* __restrict__ k,
    const float* __restrict__ v, float* __restrict__ P) {
  const int wave = threadIdx.x >> 6, lane = threadIdx.x & 63;
  const int task = (int)blockIdx.x * 4 + wave;  // 0..9215
  const int bh = task / 288, t = task % 288;
  const int b = bh >> 3, h = bh & 7;
  int g8 = 0;
  while (4 * (g8 + 1) * (g8 + 2) <= t) ++g8;
  const int r = t - 4 * g8 * (g8 + 1);
  const int qg = g8 * 8 + r / (g8 + 1);
  const int chunk = r % (g8 + 1);
  const int qi = lane & 15, ks = lane >> 4;
  const int qpos = qg * 16 + qi;
  const int n = b * 1024 + qpos;
  const float scale = 0.20412414523193154f;  // 1/sqrt(24)
  float qv[24];
  const float* qr = q + (size_t)n * 192 + h * 24;
#pragma unroll
  for (int d = 0; d < 24; ++d) qv[d] = qr[d] * scale;
  float m = -1e30f, l = 0.0f, ov[24] = {};
  const float* kbp = k + (size_t)b * 1024 * 192 + h * 24;
  const float* vbp = v + (size_t)b * 1024 * 192 + h * 24;
  const int kend = min(qpos, chunk * 128 + 127);
  for (int kp = chunk * 128 + ks; kp <= kend; kp += 4) {
    const f32x4* kr = (const f32x4*)(kbp + (size_t)kp * 192);
    float s0 = 0.0f, s1 = 0.0f, s2 = 0.0f;
#pragma unroll
    for (int j = 0; j < 2; ++j) {
      f32x4 k0 = kr[j * 3 + 0], k1 = kr[j * 3 + 1], k2 = kr[j * 3 + 2];
#pragma unroll
      for (int e = 0; e < 4; ++e) {
        s0 += qv[(j * 3 + 0) * 4 + e] * k0[e];
        s1 += qv[(j * 3 + 1) * 4 + e] * k1[e];
        s2 += qv[(j * 3 + 2) * 4 + e] * k2[e];
      }
    }
    float s = s0 + s1 + s2;
    float mn = fmaxf(m, s);
    float corr = __expf(m - mn);
    float p = __expf(s - mn);
    const f32x4* vr = (const f32x4*)(vbp + (size_t)kp * 192);
    l = l * corr + p;
#pragma unroll
    for (int j = 0; j < 6; ++j) {
      f32x4 vvv = vr[j];
#pragma unroll
      for (int e = 0; e < 4; ++e) ov[j * 4 + e] = ov[j * 4 + e] * corr + p * vvv[e];
    }
    m = mn;
  }
  // merge the 4 k-slices (lanes qi, qi+16, qi+32, qi+48)
#pragma unroll
  for (int off = 16; off < 64; off <<= 1) {
    float m2 = __shfl_xor(m, off);
    float l2 = __shfl_xor(l, off);
    float mn = fmaxf(m, m2);
    float c1 = __expf(m - mn), c2 = __expf(m2 - mn);
    l = l * c1 + l2 * c2;
#pragma unroll
    for (int d = 0; d < 24; ++d) {
      float o2 = __shfl_xor(ov[d], off);
      ov[d] = ov[d] * c1 + o2 * c2;
    }
    m = mn;
  }
  if (ks == 0) {
    float* pr = P + ((size_t)task * 16 + qi) * 28;
    pr[0] = m;
    pr[1] = l;
#pragma unroll
    for (int d = 0; d < 24; ++d) pr[2 + d] = ov[d];
  }
}

__global__ __launch_bounds__(192) void attn_merge(
    const float* __restrict__ P, unsigned short* __restrict__ o) {
  const int n = blockIdx.x;            // 0..4095
  const int tid = threadIdx.x;
  const int h = tid / 24, d = tid - h * 24;
  const int b = n >> 10, qpos = n & 1023;
  const int qg = qpos >> 4, qi = qpos & 15;
  const int g8 = qg >> 3;
  const int nch = g8 + 1;              // == qpos/128 + 1 for all qi in group
  const int bh = b * 8 + h;
  const int base = bh * 288 + 4 * g8 * (g8 + 1) + (qg - g8 * 8) * (g8 + 1);
  float M = -1e30f;
  for (int c = 0; c < nch; ++c)
    M = fmaxf(M, P[((size_t)(base + c) * 16 + qi) * 28]);
  float L = 0.0f, OV = 0.0f;
  for (int c = 0; c < nch; ++c) {
    const float* pr = P + ((size_t)(base + c) * 16 + qi) * 28;
    float w = __expf(pr[0] - M);
    L += pr[1] * w;
    OV += pr[2 + d] * w;
  }
  o[(size_t)n * 192 + h * 24 + d] = f2b(OV / L);
}

// per-row: p = dot(Dz,x)/(||Dz||+eps)^2 ; x -= p*Dz ; xb = bf16(x)
__global__ __launch_bounds__(256) void proj_update(
    const float* __restrict__ Dz, float* __restrict__ x,
    unsigned short* __restrict__ xb) {
  const int n = blockIdx.x;
  const int tid = threadIdx.x;
  const float* dz = Dz + (size_t)n * 768;
  float* xr = x + (size_t)n * 768;
  float dot = 0.0f, s2 = 0.0f;
  for (int i = tid; i < 768; i += 256) {
    float a = dz[i], c = xr[i];
    dot += a * c;
    s2 += a * a;
  }
#pragma unroll
  for (int o2 = 32; o2; o2 >>= 1) {
    dot += __shfl_down(dot, o2);
    s2 += __shfl_down(s2, o2);
  }
  __shared__ float sd[4], ss[4], sp;
  const int wave = tid >> 6, lane = tid & 63;
  if (lane == 0) { sd[wave] = dot; ss[wave] = s2; }
  __syncthreads();
  if (tid == 0) {
    float Dd = sd[0] + sd[1] + sd[2] + sd[3];
    float S = ss[0] + ss[1] + ss[2] + ss[3];
    float nrm = sqrtf(S) + 1e-6f;
    sp = Dd / (nrm * nrm);
  }
  __syncthreads();
  float p = sp;
  for (int i = tid; i < 768; i += 256) {
    float nx = xr[i] - p * dz[i];
    xr[i] = nx;
    xb[(size_t)n * 768 + i] = f2b(nx);
  }
}

DEVFN int sanitize(int v) { return (v & 0x8000) ? 0 : v; }  // -0/neg codes -> 0

// top-32 of z_novel row (bf16 codes nonneg => int order = value order);
// emits 32 (idx,val) pairs per row (slot order arbitrary).
__global__ __launch_bounds__(256) void topk_rows(
    const unsigned short* __restrict__ zbuf, int* __restrict__ idxo,
    float* __restrict__ valo) {
  const int n = blockIdx.x;
  const int b = n >> 10;
  const int tid = threadIdx.x;
  const int wave = tid >> 6, lane = tid & 63;
  const uint4v* zr = (const uint4v*)(zbuf + (size_t)(n + b + 1) * 12288);
  uint4v pk[6];
#pragma unroll
  for (int j = 0; j < 6; ++j) pk[j] = zr[tid * 6 + j];
  __shared__ int swsum[4];
  __shared__ int seq[256];
  __shared__ int spcnt;
  int lo = 0, hi = 0x7F7F;
  while (lo < hi) {
    int mid = (lo + hi) >> 1;
    int c = 0;
#pragma unroll
    for (int j = 0; j < 6; ++j)
#pragma unroll
      for (int e = 0; e < 4; ++e) {
        unsigned int u = pk[j][e];
        c += (sanitize((int)(u & 0xffffu)) > mid) + (sanitize((int)(u >> 16)) > mid);
      }
#pragma unroll
    for (int o2 = 32; o2; o2 >>= 1) c += __shfl_down(c, o2);
    if (lane == 0) swsum[wave] = c;
    __syncthreads();
    int total = swsum[0] + swsum[1] + swsum[2] + swsum[3];
    __syncthreads();
    if (total < 32) hi = mid; else lo = mid + 1;
  }
  const int T = lo;
  int cgt = 0, ceq = 0;
#pragma unroll
  for (int j = 0; j < 6; ++j)
#pragma unroll
    for (int e = 0; e < 4; ++e) {
      unsigned int u = pk[j][e];
      int v0 = sanitize((int)(u & 0xffffu)), v1 = sanitize((int)(u >> 16));
      cgt += (v0 > T) + (v1 > T);
      ceq += (v0 == T) + (v1 == T);
    }
  int cg = cgt;
#pragma unroll
  for (int o2 = 32; o2; o2 >>= 1) cg += __shfl_down(cg, o2);
  if (lane == 0) swsum[wave] = cg;
  seq[tid] = ceq;
  if (tid == 0) spcnt = 0;
  __syncthreads();
  const int total_gt = swsum[0] + swsum[1] + swsum[2] + swsum[3];
  for (int o2 = 1; o2 < 256; o2 <<= 1) {
    int vv = (tid >= o2) ? seq[tid - o2] : 0;
    __syncthreads();
    seq[tid] += vv;
    __syncthreads();
  }
  const int quota = 32 - total_gt;
  int rank = seq[tid] - ceq;
  int* irow = idxo + (size_t)n * 32;
  float* vrow = valo + (size_t)n * 32;
#pragma unroll
  for (int j = 0; j < 6; ++j)
#pragma unroll
    for (int e = 0; e < 4; ++e) {
      unsigned int u = pk[j][e];
#pragma unroll
      for (int hf = 0; hf < 2; ++hf) {
        int v = sanitize(hf ? (int)(u >> 16) : (int)(u & 0xffffu));
        bool kp = false;
        if (v > T) kp = true;
        else if (v == T) { if (rank < quota) kp = true; ++rank; }
        if (kp) {
          int pos = atomicAdd(&spcnt, 1);
          irow[pos] = tid * 48 + j * 8 + e * 2 + hf;
          vrow[pos] = b2f((unsigned short)v);
        }
      }
    }
}

// out = x_input - x_final + sum_j val_j * D[idx_j,:]   (f32 in, f32 out)
__global__ __launch_bounds__(256) void sparse_recons(
    const int* __restrict__ idxo, const float* __restrict__ valo,
    const float* __restrict__ x, const float* __restrict__ xin,
    const float* __restrict__ D, float* __restrict__ out) {
  const int n = blockIdx.x;
  const int t = threadIdx.x;
  __shared__ int sidx[32];
  __shared__ float sval[32];
  if (t < 32) { sidx[t] = idxo[(size_t)n * 32 + t]; sval[t] = valo[(size_t)n * 32 + t]; }
  __syncthreads();
  float acc[3];
#pragma unroll
  for (int u = 0; u < 3; ++u) {
    size_t i = (size_t)n * 768 + t + u * 256;
    acc[u] = xin[i] - x[i];
  }
  for (int j = 0; j < 32; ++j) {
    size_t base = (size_t)sidx[j] * 768;
    float vj = sval[j];
#pragma unroll
    for (int u = 0; u < 3; ++u) acc[u] += vj * D[base + t + u * 256];
  }
#pragma unroll
  for (int u = 0; u < 3; ++u) out[(size_t)n * 768 + t + u * 256] = acc[u];
}

// ===========================================================================
extern "C" void kernel_launch(void* const* d_in, const int* in_sizes, int n_in,
                              void* d_out, int out_size, void* d_ws, size_t ws_size,
                              hipStream_t stream) {
  (void)in_sizes; (void)n_in;
  const float* xin  = (const float*)d_in[0];
  const float* D    = (const float*)d_in[1];
  const float* bvec = (const float*)d_in[2];
  const float* Wq   = (const float*)d_in[3];
  const float* bq   = (const float*)d_in[4];
  const float* Wk   = (const float*)d_in[5];
  const float* bk   = (const float*)d_in[6];
  const float* Wv   = (const float*)d_in[7];
  const float* bv   = (const float*)d_in[8];
  const float* Wo   = (const float*)d_in[9];
  const float* bo   = (const float*)d_in[10];
  const float LAM = 1.0f / 3072.0f;

  char* ws = (char*)d_ws;
  size_t off = 0;
  auto alloc = [&](size_t bytes) {
    void* p = ws + off;
    off += (bytes + 255) & ~(size_t)255;
    return p;
  };
  unsigned short* zbuf = (unsigned short*)alloc((size_t)4 * 1025 * 12288 * 2);
  unsigned short* zpred_ = zbuf;  // alias: lifetimes disjoint
  float* attnP = (float*)zbuf;    // alias: partials live between qkv and Wo GEMMs
  float* x           = (float*)alloc((size_t)4096 * 768 * 4);
  unsigned short* xb = (unsigned short*)alloc((size_t)4096 * 768 * 2);
  float* qb  = (float*)alloc((size_t)4096 * 192 * 4);
  float* kb  = (float*)alloc((size_t)4096 * 192 * 4);
  float* vb  = (float*)alloc((size_t)4096 * 192 * 4);
  unsigned short* ob = (unsigned short*)alloc((size_t)4096 * 192 * 2);
  float* Dz  = (float*)alloc((size_t)4096 * 768 * 4);
  int* idxo  = (int*)alloc((size_t)4096 * 32 * 4);
  float* valo = (float*)alloc((size_t)4096 * 32 * 4);
  const size_t WQKV = (size_t)192 * 12288;   // per (layer, weight)
  unsigned short* WqkvT = (unsigned short*)alloc((size_t)6 * WQKV * 2);
  unsigned short* WoT   = (unsigned short*)alloc((size_t)2 * 12288 * 192 * 2);
  unsigned short* Dbt   = (unsigned short*)alloc((size_t)12288 * 768 * 2);
  unsigned short* Dt    = (unsigned short*)alloc((size_t)768 * 12288 * 2);
  const size_t NEED = off;  // ~219.8 MB (confirmed fitting in R5/R6)
  // qkv split-1 partials alias the (dead at qkv time) Dz buffer: 9.44 MB <= 12.6 MB
  float* P2 = Dz;

  if (ws_size < NEED) {  // safety net (should never fire)
    fill_out_zero<<<(out_size + 255) / 256, 256, 0, stream>>>((float*)d_out, out_size);
    return;
  }

  init_x<<<12288, 256, 0, stream>>>(xin, bvec, x, xb);
  conv_f2b<<<9216, 256, 0, stream>>>(D, Dbt);
  transpose_f2b<<<dim3(384, 24), 256, 0, stream>>>(D, Dt, 12288, 768);
  for (int l = 0; l < 2; ++l) {
    transpose_f2b<<<dim3(384, 6), 256, 0, stream>>>(
        Wq + (size_t)l * 12288 * 192, WqkvT + (size_t)(l * 3 + 0) * WQKV, 12288, 192);
    transpose_f2b<<<dim3(384, 6), 256, 0, stream>>>(
        Wk + (size_t)l * 12288 * 192, WqkvT + (size_t)(l * 3 + 1) * WQKV, 12288, 192);
    transpose_f2b<<<dim3(384, 6), 256, 0, stream>>>(
        Wv + (size_t)l * 12288 * 192, WqkvT + (size_t)(l * 3 + 2) * WQKV, 12288, 192);
    transpose_f2b<<<dim3(6, 384), 256, 0, stream>>>(
        Wo + (size_t)l * 192 * 12288, WoT + (size_t)l * 12288 * 192, 192, 12288);
  }

  for (int l = 0; l < 2; ++l) {
    // z_in = relu(LAM * x @ D^T) -> zbuf shifted rows [b*1025+1 ..]
    // 256^2 tile: grid 16x48 -> 1-D 768, XCD-rect 16x x 6y (B 2.4 MB/XCD)
    gemm_bt2<unsigned short, true, 1, false, false, 16, 48, 1, 16, 6>
        <<<768, 512, 0, stream>>>(xb, Dbt, zbuf, nullptr, 768, 12288, LAM);
    // k/v row-0 prefill (= zero-context bias row); qb fully written by qkv s=0.
    fill_bias<<<3072, 256, 0, stream>>>(kb, bk + (size_t)l * 192, 192);
    fill_bias<<<3072, 256, 0, stream>>>(vb, bv + (size_t)l * 192, 192);
    // P2 zero-prefill (rows (b,0) of k/v planes must read as 0 in the merge)
    fill_bias<<<9216, 256, 0, stream>>>(P2, nullptr, 192);
    // atomic-free fused q/k/v: split 0 -> final bufs, split 1 -> P2; merge.
    gemm_qkv<<<384, 256, 0, stream>>>(
        zbuf, WqkvT + (size_t)(l * 3) * WQKV,
        bq + (size_t)l * 192, bk + (size_t)l * 192, bv + (size_t)l * 192,
        qb, kb, vb, P2);
    qkv_merge<<<2304, 256, 0, stream>>>(P2, qb, kb, vb);
    // Attention (z_in in zbuf is dead now; attnP scratch aliases it)
    attn_pass1<<<2304, 256, 0, stream>>>(qb, kb, vb, attnP);
    attn_merge<<<4096, 192, 0, stream>>>(attnP, ob);
    // z_pred_ = relu(o @ Wo + bo) -> zpred_ (aliases zbuf; attnP dead)
    gemm_bt2<unsigned short, true, 0, true, false, 16, 48, 1, 16, 6>
        <<<768, 512, 0, stream>>>(
        ob, WoT + (size_t)l * 12288 * 192, zpred_, bo + (size_t)l * 12288, 192, 12288, 1.0f);
    // Dz = z_pred_ @ D  (256^2, split-K=4 -> 192 blocks; atomics stay at the
    // proven-harmless 49 MB; each XCD-pair owns one k-split, B L2-resident)
    fill_bias<<<12288, 256, 0, stream>>>(Dz, nullptr, 768);
    gemm_bt2<float, false, 0, false, true, 16, 3, 4, 8, 3>
        <<<192, 512, 0, stream>>>(zpred_, Dt, Dz, nullptr, 12288, 768, 1.0f);
    proj_update<<<4096, 256, 0, stream>>>(Dz, x, xb);
  }
  // z_novel = relu(LAM * x @ D^T) -> zbuf shifted rows
  gemm_bt2<unsigned short, true, 1, false, false, 16, 48, 1, 16, 6>
      <<<768, 512, 0, stream>>>(xb, Dbt, zbuf, nullptr, 768, 12288, LAM);
  topk_rows<<<4096, 256, 0, stream>>>(zbuf, idxo, valo);
  sparse_recons<<<4096, 256, 0, stream>>>(idxo, valo, x, xin, D, (float*)d_out);
}